// Round 1
// baseline (1304.224 us; speedup 1.0000x reference)
//
#include <hip/hip_runtime.h>
#include <math.h>

#define BB   8
#define CIN  512
#define NSP  2304
#define DKD  64
#define OCH  640   // 64(q)+64(k)+512(v)
#define LL   48

// ---------------------------------------------------------------------------
// stack Wq/Wk/Wv into one (640 x 512) matrix + stacked bias
__global__ __launch_bounds__(256) void stack_w(
    const float* __restrict__ Wq, const float* __restrict__ bq,
    const float* __restrict__ Wk, const float* __restrict__ bk,
    const float* __restrict__ Wv, const float* __restrict__ bv,
    float* __restrict__ Wst, float* __restrict__ bst) {
  int idx = blockIdx.x * 256 + threadIdx.x;   // 640*512
  int row = idx >> 9;
  float val;
  if (row < 64)       val = Wq[idx];
  else if (row < 128) val = Wk[idx - (64 << 9)];
  else                val = Wv[idx - (128 << 9)];
  Wst[idx] = val;
  if (idx < OCH) {
    float bval;
    if (idx < 64)       bval = bq[idx];
    else if (idx < 128) bval = bk[idx - 64];
    else                bval = bv[idx - 128];
    bst[idx] = bval;
  }
}

// build PhT/PwT: PT[d, n] = rel[(n%48)-(n/48)+47, d]   (64 x 2304 each)
__global__ __launch_bounds__(256) void prep_pt(
    const float* __restrict__ rel_rows, const float* __restrict__ rel_cols,
    float* __restrict__ PhT, float* __restrict__ PwT) {
  int idx = blockIdx.x * 256 + threadIdx.x;   // 64*2304
  int d = idx / NSP;
  int n = idx - d * NSP;
  int xr = n / LL;
  int ic = n - xr * LL;
  int shift = ic - xr + (LL - 1);
  PhT[idx] = rel_rows[shift * 64 + d];
  PwT[idx] = rel_cols[shift * 64 + d];
}

// ---------------------------------------------------------------------------
// proj: y[b,o,n] = sum_c Wst[o,c]*x[b,c,n] + bst[o]
// grid (NSP/64, OCH/64, B), 256 thr, 64x64 tile, 4x4/thread
__global__ __launch_bounds__(256) void proj_gemm(
    const float* __restrict__ Wst, const float* __restrict__ bst,
    const float* __restrict__ x, float* __restrict__ y) {
  __shared__ float As[16][68];
  __shared__ float Bs[16][68];
  const int b = blockIdx.z;
  const int row0 = blockIdx.y * 64;
  const int col0 = blockIdx.x * 64;
  const float* __restrict__ Bp = x + (size_t)b * CIN * NSP;
  const int tid = threadIdx.x;
  const int tx = tid & 15, ty = tid >> 4;
  float acc[4][4] = {{0.f, 0.f, 0.f, 0.f}};
  for (int k0 = 0; k0 < CIN; k0 += 16) {
#pragma unroll
    for (int l = 0; l < 4; l++) {
      int idx = tid + l * 256;
      int m = idx >> 4, kk = idx & 15;
      As[kk][m] = Wst[(size_t)(row0 + m) * CIN + (k0 + kk)];
    }
#pragma unroll
    for (int l = 0; l < 4; l++) {
      int idx = tid + l * 256;
      int kk = idx >> 6, n = idx & 63;
      Bs[kk][n] = Bp[(size_t)(k0 + kk) * NSP + (col0 + n)];
    }
    __syncthreads();
#pragma unroll
    for (int kk = 0; kk < 16; kk++) {
      float a0[4], b0[4];
#pragma unroll
      for (int i = 0; i < 4; i++) a0[i] = As[kk][ty * 4 + i];
#pragma unroll
      for (int j = 0; j < 4; j++) b0[j] = Bs[kk][tx * 4 + j];
#pragma unroll
      for (int i = 0; i < 4; i++)
#pragma unroll
        for (int j = 0; j < 4; j++) acc[i][j] += a0[i] * b0[j];
    }
    __syncthreads();
  }
  float* __restrict__ Cp = y + (size_t)b * OCH * NSP;
#pragma unroll
  for (int i = 0; i < 4; i++) {
    int r = row0 + ty * 4 + i;
    float bias = bst[r];
#pragma unroll
    for (int j = 0; j < 4; j++)
      Cp[(size_t)r * NSP + (col0 + tx * 4 + j)] = acc[i][j] + bias;
  }
}

// ---------------------------------------------------------------------------
// per-channel BN batch stats over (B, NSP), fold scale/bias -> a,b
__global__ __launch_bounds__(256) void bn_stats(
    const float* __restrict__ y,
    const float* __restrict__ qs_, const float* __restrict__ qb_,
    const float* __restrict__ ks_, const float* __restrict__ kb_,
    const float* __restrict__ vs_, const float* __restrict__ vb_,
    float* __restrict__ chanA, float* __restrict__ chanB) {
  const int ch = blockIdx.x;
  const int tid = threadIdx.x;
  float s = 0.f, s2 = 0.f;
  for (int b = 0; b < BB; b++) {
    const float* p = y + ((size_t)b * OCH + ch) * NSP;
    for (int n = tid; n < NSP; n += 256) {
      float v = p[n];
      s += v;
      s2 += v * v;
    }
  }
  __shared__ float sb[8];
#pragma unroll
  for (int off = 32; off > 0; off >>= 1) {
    s += __shfl_down(s, off);
    s2 += __shfl_down(s2, off);
  }
  int lane = tid & 63, wid = tid >> 6;
  if (lane == 0) { sb[wid] = s; sb[4 + wid] = s2; }
  __syncthreads();
  if (tid == 0) {
    float ts  = sb[0] + sb[1] + sb[2] + sb[3];
    float ts2 = sb[4] + sb[5] + sb[6] + sb[7];
    const float inv = 1.f / (float)(BB * NSP);
    float mean = ts * inv;
    float var  = ts2 * inv - mean * mean;
    float scale, bias;
    if (ch < 64)       { scale = qs_[ch];       bias = qb_[ch]; }
    else if (ch < 128) { scale = ks_[ch - 64];  bias = kb_[ch - 64]; }
    else               { scale = vs_[ch - 128]; bias = vb_[ch - 128]; }
    float a = scale * rsqrtf(var + 1e-5f);
    chanA[ch] = a;
    chanB[ch] = bias - mean * a;
  }
}

// y = relu(a[ch]*y + b[ch]) in-place, float4
__global__ __launch_bounds__(256) void bn_apply(
    float* __restrict__ y, const float* __restrict__ chanA,
    const float* __restrict__ chanB) {
  size_t i4 = (size_t)blockIdx.x * 256 + threadIdx.x;
  size_t i = i4 * 4;
  int ch = (int)((i / NSP) % OCH);
  float a = chanA[ch], bo = chanB[ch];
  float4 v = *(const float4*)(y + i);
  v.x = fmaxf(0.f, a * v.x + bo);
  v.y = fmaxf(0.f, a * v.y + bo);
  v.z = fmaxf(0.f, a * v.z + bo);
  v.w = fmaxf(0.f, a * v.w + bo);
  *(float4*)(y + i) = v;
}

// ---------------------------------------------------------------------------
// energy: E[b,i,j] = sum_d q[b,d,i]*k[b,d,j]  (both operands K-major)
// grid (NSP/64 j, NSP/64 i, B)
__global__ __launch_bounds__(256) void energy_gemm(
    const float* __restrict__ qkv, float* __restrict__ E) {
  __shared__ float As[16][68];
  __shared__ float Bs[16][68];
  const int b = blockIdx.z;
  const int row0 = blockIdx.y * 64;  // i
  const int col0 = blockIdx.x * 64;  // j
  const float* __restrict__ q = qkv + (size_t)b * OCH * NSP;
  const float* __restrict__ k = q + (size_t)64 * NSP;
  const int tid = threadIdx.x;
  const int tx = tid & 15, ty = tid >> 4;
  float acc[4][4] = {{0.f, 0.f, 0.f, 0.f}};
  for (int k0 = 0; k0 < DKD; k0 += 16) {
#pragma unroll
    for (int l = 0; l < 4; l++) {
      int idx = tid + l * 256;
      int kk = idx >> 6, m = idx & 63;
      As[kk][m] = q[(size_t)(k0 + kk) * NSP + row0 + m];
      Bs[kk][m] = k[(size_t)(k0 + kk) * NSP + col0 + m];
    }
    __syncthreads();
#pragma unroll
    for (int kk = 0; kk < 16; kk++) {
      float a0[4], b0[4];
#pragma unroll
      for (int i = 0; i < 4; i++) a0[i] = As[kk][ty * 4 + i];
#pragma unroll
      for (int j = 0; j < 4; j++) b0[j] = Bs[kk][tx * 4 + j];
#pragma unroll
      for (int i = 0; i < 4; i++)
#pragma unroll
        for (int j = 0; j < 4; j++) acc[i][j] += a0[i] * b0[j];
    }
    __syncthreads();
  }
  float* __restrict__ Ep = E + (size_t)b * NSP * NSP;
#pragma unroll
  for (int i = 0; i < 4; i++)
#pragma unroll
    for (int j = 0; j < 4; j++)
      Ep[(size_t)(row0 + ty * 4 + i) * NSP + (col0 + tx * 4 + j)] = acc[i][j];
}

// in-place softmax over last axis; one block per row (B*NSP rows)
__global__ __launch_bounds__(256) void softmax_rows(float* __restrict__ E) {
  const size_t row = blockIdx.x;
  float* p = E + row * NSP;
  const int tid = threadIdx.x;
  float v[9];
  float mx = -1e30f;
#pragma unroll
  for (int t = 0; t < 9; t++) {
    v[t] = p[tid + t * 256];
    mx = fmaxf(mx, v[t]);
  }
  __shared__ float sb[8];
#pragma unroll
  for (int off = 32; off > 0; off >>= 1) mx = fmaxf(mx, __shfl_down(mx, off));
  int lane = tid & 63, wid = tid >> 6;
  if (lane == 0) sb[wid] = mx;
  __syncthreads();
  mx = fmaxf(fmaxf(sb[0], sb[1]), fmaxf(sb[2], sb[3]));
  float s = 0.f;
#pragma unroll
  for (int t = 0; t < 9; t++) {
    v[t] = __expf(v[t] - mx);
    s += v[t];
  }
#pragma unroll
  for (int off = 32; off > 0; off >>= 1) s += __shfl_down(s, off);
  if (lane == 0) sb[4 + wid] = s;
  __syncthreads();
  float inv = 1.f / (sb[4] + sb[5] + sb[6] + sb[7]);
#pragma unroll
  for (int t = 0; t < 9; t++) p[tid + t * 256] = v[t] * inv;
}

// ---------------------------------------------------------------------------
// NT gemm: C[m,n] = sum_k A[m,k]*B[n,k]  (both operands K-contiguous rows)
// grid (Ncols/64, Mrows/64, B)
__global__ __launch_bounds__(256) void nt_gemm(
    const float* __restrict__ A, const float* __restrict__ B,
    float* __restrict__ C, int K, int lda, int ldb, int ldc,
    size_t strA, size_t strB, size_t strC) {
  __shared__ float As[16][68];
  __shared__ float Bs[16][68];
  const int b = blockIdx.z;
  const int row0 = blockIdx.y * 64;
  const int col0 = blockIdx.x * 64;
  const float* __restrict__ Ap = A + (size_t)b * strA;
  const float* __restrict__ Bp = B + (size_t)b * strB;
  const int tid = threadIdx.x;
  const int tx = tid & 15, ty = tid >> 4;
  float acc[4][4] = {{0.f, 0.f, 0.f, 0.f}};
  for (int k0 = 0; k0 < K; k0 += 16) {
#pragma unroll
    for (int l = 0; l < 4; l++) {
      int idx = tid + l * 256;
      int m = idx >> 4, kk = idx & 15;
      As[kk][m] = Ap[(size_t)(row0 + m) * lda + (k0 + kk)];
      Bs[kk][m] = Bp[(size_t)(col0 + m) * ldb + (k0 + kk)];
    }
    __syncthreads();
#pragma unroll
    for (int kk = 0; kk < 16; kk++) {
      float a0[4], b0[4];
#pragma unroll
      for (int i = 0; i < 4; i++) a0[i] = As[kk][ty * 4 + i];
#pragma unroll
      for (int j = 0; j < 4; j++) b0[j] = Bs[kk][tx * 4 + j];
#pragma unroll
      for (int i = 0; i < 4; i++)
#pragma unroll
        for (int j = 0; j < 4; j++) acc[i][j] += a0[i] * b0[j];
    }
    __syncthreads();
  }
  float* __restrict__ Cp = C + (size_t)b * strC;
#pragma unroll
  for (int i = 0; i < 4; i++)
#pragma unroll
    for (int j = 0; j < 4; j++)
      Cp[(size_t)(row0 + ty * 4 + i) * ldc + (col0 + tx * 4 + j)] = acc[i][j];
}

// qs[b,d] = sum_m q[b,d,m]
__global__ __launch_bounds__(256) void qsum_kernel(
    const float* __restrict__ qkv, float* __restrict__ qs) {
  int bd = blockIdx.x;
  int b = bd >> 6, d = bd & 63;
  const float* p = qkv + ((size_t)b * OCH + d) * NSP;
  float s = 0.f;
  for (int n = threadIdx.x; n < NSP; n += 256) s += p[n];
  __shared__ float sb[4];
#pragma unroll
  for (int off = 32; off > 0; off >>= 1) s += __shfl_down(s, off);
  int lane = threadIdx.x & 63, wid = threadIdx.x >> 6;
  if (lane == 0) sb[wid] = s;
  __syncthreads();
  if (threadIdx.x == 0) qs[bd] = sb[0] + sb[1] + sb[2] + sb[3];
}

// closed-form BN stats for Eh/Ew: mean_c = sum_{b,d} u*qs / (B*N),
// E2_c = sum_b u^T Gq u / (B*N);   g = scale*rsqrt(var+eps), off = bias-mean*g
__global__ __launch_bounds__(64) void rel_stats(
    const float* __restrict__ Uh, const float* __restrict__ Uw,
    const float* __restrict__ Gq, const float* __restrict__ qs,
    const float* __restrict__ bnr_s, const float* __restrict__ bnr_b,
    const float* __restrict__ bnc_s, const float* __restrict__ bnc_b,
    float* __restrict__ gh, float* __restrict__ gw, float* __restrict__ offc) {
  const int c = blockIdx.x;
  const int d = threadIdx.x;
  __shared__ float su[2][64];
  float s1h = 0.f, s2h = 0.f, s1w = 0.f, s2w = 0.f;
  for (int b = 0; b < BB; b++) {
    float uh = Uh[((size_t)b * CIN + c) * 64 + d];
    float uw = Uw[((size_t)b * CIN + c) * 64 + d];
    __syncthreads();
    su[0][d] = uh;
    su[1][d] = uw;
    __syncthreads();
    const float* G = Gq + (size_t)b * 4096 + d * 64;
    float th = 0.f, tw = 0.f;
    for (int e = 0; e < 64; e++) {
      float g = G[e];
      th += g * su[0][e];
      tw += g * su[1][e];
    }
    float qsd = qs[b * 64 + d];
    s1h += uh * qsd;
    s2h += uh * th;
    s1w += uw * qsd;
    s2w += uw * tw;
  }
#pragma unroll
  for (int off = 32; off > 0; off >>= 1) {
    s1h += __shfl_down(s1h, off);
    s2h += __shfl_down(s2h, off);
    s1w += __shfl_down(s1w, off);
    s2w += __shfl_down(s2w, off);
  }
  if (d == 0) {
    const float inv = 1.f / (float)(BB * NSP);
    float mh = s1h * inv, vh = s2h * inv - mh * mh;
    float mw = s1w * inv, vw = s2w * inv - mw * mw;
    float gch = bnr_s[c] * rsqrtf(vh + 1e-5f);
    float gcw = bnc_s[c] * rsqrtf(vw + 1e-5f);
    gh[c] = gch;
    gw[c] = gcw;
    offc[c] = (bnr_b[c] - mh * gch) + (bnc_b[c] - mw * gcw);
  }
}

// UcT[b,d,c] = Uh[b,c,d]*gh[c] + Uw[b,c,d]*gw[c]
__global__ __launch_bounds__(256) void combine_u(
    const float* __restrict__ Uh, const float* __restrict__ Uw,
    const float* __restrict__ gh, const float* __restrict__ gw,
    float* __restrict__ UcT) {
  int idx = blockIdx.x * 256 + threadIdx.x;  // B*64*512
  int c = idx & 511;
  int d = (idx >> 9) & 63;
  int b = idx >> 15;
  size_t src = ((size_t)b * CIN + c) * 64 + d;
  UcT[idx] = Uh[src] * gh[c] + Uw[src] * gw[c];
}

// ---------------------------------------------------------------------------
// final: dst[b,c,m] = gamma*( out[b,c,m] + sum_d UcT[b,d,c]*q[b,d,m] + offc[c] ) + x[b,c,m]
// grid (NSP/64, CIN/64, B); K=64 (both operands K-major)
__global__ __launch_bounds__(256) void final_gemm(
    const float* __restrict__ UcT, const float* __restrict__ qkv,
    const float* __restrict__ outb, const float* __restrict__ x,
    const float* __restrict__ offc, const float* __restrict__ gamma,
    float* __restrict__ dst) {
  __shared__ float As[16][68];
  __shared__ float Bs[16][68];
  const int b = blockIdx.z;
  const int row0 = blockIdx.y * 64;  // c
  const int col0 = blockIdx.x * 64;  // m
  const float* __restrict__ Ap = UcT + (size_t)b * 64 * CIN;  // [d, c]
  const float* __restrict__ Bp = qkv + (size_t)b * OCH * NSP; // q: [d, m]
  const int tid = threadIdx.x;
  const int tx = tid & 15, ty = tid >> 4;
  float acc[4][4] = {{0.f, 0.f, 0.f, 0.f}};
  for (int k0 = 0; k0 < DKD; k0 += 16) {
#pragma unroll
    for (int l = 0; l < 4; l++) {
      int idx = tid + l * 256;
      int kk = idx >> 6, m = idx & 63;
      As[kk][m] = Ap[(size_t)(k0 + kk) * CIN + row0 + m];
      Bs[kk][m] = Bp[(size_t)(k0 + kk) * NSP + col0 + m];
    }
    __syncthreads();
#pragma unroll
    for (int kk = 0; kk < 16; kk++) {
      float a0[4], b0[4];
#pragma unroll
      for (int i = 0; i < 4; i++) a0[i] = As[kk][ty * 4 + i];
#pragma unroll
      for (int j = 0; j < 4; j++) b0[j] = Bs[kk][tx * 4 + j];
#pragma unroll
      for (int i = 0; i < 4; i++)
#pragma unroll
        for (int j = 0; j < 4; j++) acc[i][j] += a0[i] * b0[j];
    }
    __syncthreads();
  }
  const float g = gamma[0];
  const float* __restrict__ op = outb + (size_t)b * CIN * NSP;
  const float* __restrict__ xp = x + (size_t)b * CIN * NSP;
  float* __restrict__ dp = dst + (size_t)b * CIN * NSP;
#pragma unroll
  for (int i = 0; i < 4; i++) {
    int c = row0 + ty * 4 + i;
    float off = offc[c];
#pragma unroll
    for (int j = 0; j < 4; j++) {
      size_t o = (size_t)c * NSP + (col0 + tx * 4 + j);
      dp[o] = g * (op[o] + acc[i][j] + off) + xp[o];
    }
  }
}

// ---------------------------------------------------------------------------
extern "C" void kernel_launch(void* const* d_in, const int* in_sizes, int n_in,
                              void* d_out, int out_size, void* d_ws, size_t ws_size,
                              hipStream_t stream) {
  const float* x        = (const float*)d_in[0];
  const float* Wq       = (const float*)d_in[1];
  const float* bq       = (const float*)d_in[2];
  const float* q_scale  = (const float*)d_in[3];
  const float* q_bias   = (const float*)d_in[4];
  const float* Wk       = (const float*)d_in[5];
  const float* bk       = (const float*)d_in[6];
  const float* k_scale  = (const float*)d_in[7];
  const float* k_bias   = (const float*)d_in[8];
  const float* Wv       = (const float*)d_in[9];
  const float* bv       = (const float*)d_in[10];
  const float* v_scale  = (const float*)d_in[11];
  const float* v_bias   = (const float*)d_in[12];
  const float* rel_rows = (const float*)d_in[13];
  const float* rel_cols = (const float*)d_in[14];
  const float* bnr_s    = (const float*)d_in[15];
  const float* bnr_b    = (const float*)d_in[16];
  const float* bnc_s    = (const float*)d_in[17];
  const float* bnc_b    = (const float*)d_in[18];
  const float* gamma    = (const float*)d_in[19];
  float* dst = (float*)d_out;

  float* ws = (float*)d_ws;
  size_t o = 0;
  float* Wst    = ws + o; o += (size_t)OCH * CIN;   // 327680
  float* bst    = ws + o; o += OCH;
  float* chanA  = ws + o; o += OCH;
  float* chanB  = ws + o; o += OCH;
  float* PhT    = ws + o; o += (size_t)64 * NSP;
  float* PwT    = ws + o; o += (size_t)64 * NSP;
  float* qkv    = ws + o; o += (size_t)BB * OCH * NSP;   // 11.8M
  float* energy = ws + o; o += (size_t)BB * NSP * NSP;   // 42.5M
  float* outb   = ws + o; o += (size_t)BB * CIN * NSP;   // 9.4M
  float* Uh     = ws + o; o += (size_t)BB * CIN * 64;
  float* Uw     = ws + o; o += (size_t)BB * CIN * 64;
  float* UcT    = ws + o; o += (size_t)BB * 64 * CIN;
  float* Gq     = ws + o; o += (size_t)BB * 64 * 64;
  float* qs     = ws + o; o += (size_t)BB * 64;
  float* gh     = ws + o; o += CIN;
  float* gw     = ws + o; o += CIN;
  float* offc   = ws + o; o += CIN;

  // prep
  stack_w<<<(OCH * CIN) / 256, 256, 0, stream>>>(Wq, bq, Wk, bk, Wv, bv, Wst, bst);
  prep_pt<<<(64 * NSP) / 256, 256, 0, stream>>>(rel_rows, rel_cols, PhT, PwT);

  // qkv projection + BN + relu
  proj_gemm<<<dim3(NSP / 64, OCH / 64, BB), 256, 0, stream>>>(Wst, bst, x, qkv);
  bn_stats<<<OCH, 256, 0, stream>>>(qkv, q_scale, q_bias, k_scale, k_bias,
                                    v_scale, v_bias, chanA, chanB);
  bn_apply<<<(size_t)BB * OCH * NSP / 4 / 256, 256, 0, stream>>>(qkv, chanA, chanB);

  // attention
  energy_gemm<<<dim3(NSP / 64, NSP / 64, BB), 256, 0, stream>>>(qkv, energy);
  softmax_rows<<<BB * NSP, 256, 0, stream>>>(energy);

  // rel-position small GEMMs: Uh = v@PhT^T, Uw, Gq = q q^T
  nt_gemm<<<dim3(1, CIN / 64, BB), 256, 0, stream>>>(
      qkv + (size_t)128 * NSP, PhT, Uh, NSP, NSP, NSP, 64,
      (size_t)OCH * NSP, 0, (size_t)CIN * 64);
  nt_gemm<<<dim3(1, CIN / 64, BB), 256, 0, stream>>>(
      qkv + (size_t)128 * NSP, PwT, Uw, NSP, NSP, NSP, 64,
      (size_t)OCH * NSP, 0, (size_t)CIN * 64);
  nt_gemm<<<dim3(1, 1, BB), 256, 0, stream>>>(
      qkv, qkv, Gq, NSP, NSP, NSP, 64,
      (size_t)OCH * NSP, (size_t)OCH * NSP, (size_t)64 * 64);
  qsum_kernel<<<BB * 64, 256, 0, stream>>>(qkv, qs);
  rel_stats<<<CIN, 64, 0, stream>>>(Uh, Uw, Gq, qs, bnr_s, bnr_b, bnc_s, bnc_b,
                                    gh, gw, offc);
  combine_u<<<(BB * 64 * CIN) / 256, 256, 0, stream>>>(Uh, Uw, gh, gw, UcT);

  // out[b,c,i] = sum_j v[b,c,j] * att[b,i,j]   (the big one)
  nt_gemm<<<dim3(NSP / 64, CIN / 64, BB), 256, 0, stream>>>(
      qkv + (size_t)128 * NSP, energy, outb, NSP, NSP, NSP, NSP,
      (size_t)OCH * NSP, (size_t)NSP * NSP, (size_t)CIN * NSP);

  // final epilogue GEMM (K=64) + combine + residual
  final_gemm<<<dim3(NSP / 64, CIN / 64, BB), 256, 0, stream>>>(
      UcT, qkv, outb, x, offc, gamma, dst);
}

// Round 2
// 821.319 us; speedup vs baseline: 1.5880x; 1.5880x over previous
//
#include <hip/hip_runtime.h>
#include <math.h>

#define BB   8
#define CIN  512
#define NSP  2304
#define DKD  64
#define OCH  640   // 64(q)+64(k)+512(v)
#define LL   48

typedef __attribute__((ext_vector_type(8))) short bf16x8;
typedef __attribute__((ext_vector_type(4))) float f32x4;

__device__ inline unsigned short f2bf(float f) {
  unsigned int u = __float_as_uint(f);
  unsigned int r = (u + 0x7fffu + ((u >> 16) & 1u)) >> 16;   // RNE
  return (unsigned short)r;
}

// ---------------------------------------------------------------------------
// stack Wq/Wk/Wv into one (640 x 512) matrix + stacked bias
__global__ __launch_bounds__(256) void stack_w(
    const float* __restrict__ Wq, const float* __restrict__ bq,
    const float* __restrict__ Wk, const float* __restrict__ bk,
    const float* __restrict__ Wv, const float* __restrict__ bv,
    float* __restrict__ Wst, float* __restrict__ bst) {
  int idx = blockIdx.x * 256 + threadIdx.x;   // 640*512
  int row = idx >> 9;
  float val;
  if (row < 64)       val = Wq[idx];
  else if (row < 128) val = Wk[idx - (64 << 9)];
  else                val = Wv[idx - (128 << 9)];
  Wst[idx] = val;
  if (idx < OCH) {
    float bval;
    if (idx < 64)       bval = bq[idx];
    else if (idx < 128) bval = bk[idx - 64];
    else                bval = bv[idx - 128];
    bst[idx] = bval;
  }
}

// build PhT/PwT: PT[d, n] = rel[(n%48)-(n/48)+47, d]   (64 x 2304 each)
__global__ __launch_bounds__(256) void prep_pt(
    const float* __restrict__ rel_rows, const float* __restrict__ rel_cols,
    float* __restrict__ PhT, float* __restrict__ PwT) {
  int idx = blockIdx.x * 256 + threadIdx.x;   // 64*2304
  int d = idx / NSP;
  int n = idx - d * NSP;
  int xr = n / LL;
  int ic = n - xr * LL;
  int shift = ic - xr + (LL - 1);
  PhT[idx] = rel_rows[shift * 64 + d];
  PwT[idx] = rel_cols[shift * 64 + d];
}

// ---------------------------------------------------------------------------
// proj: y[b,o,n] = sum_c Wst[o,c]*x[b,c,n] + bst[o]
__global__ __launch_bounds__(256) void proj_gemm(
    const float* __restrict__ Wst, const float* __restrict__ bst,
    const float* __restrict__ x, float* __restrict__ y) {
  __shared__ float As[16][68];
  __shared__ float Bs[16][68];
  const int b = blockIdx.z;
  const int row0 = blockIdx.y * 64;
  const int col0 = blockIdx.x * 64;
  const float* __restrict__ Bp = x + (size_t)b * CIN * NSP;
  const int tid = threadIdx.x;
  const int tx = tid & 15, ty = tid >> 4;
  float acc[4][4] = {{0.f, 0.f, 0.f, 0.f}};
  for (int k0 = 0; k0 < CIN; k0 += 16) {
#pragma unroll
    for (int l = 0; l < 4; l++) {
      int idx = tid + l * 256;
      int m = idx >> 4, kk = idx & 15;
      As[kk][m] = Wst[(size_t)(row0 + m) * CIN + (k0 + kk)];
    }
#pragma unroll
    for (int l = 0; l < 4; l++) {
      int idx = tid + l * 256;
      int kk = idx >> 6, n = idx & 63;
      Bs[kk][n] = Bp[(size_t)(k0 + kk) * NSP + (col0 + n)];
    }
    __syncthreads();
#pragma unroll
    for (int kk = 0; kk < 16; kk++) {
      float a0[4], b0[4];
#pragma unroll
      for (int i = 0; i < 4; i++) a0[i] = As[kk][ty * 4 + i];
#pragma unroll
      for (int j = 0; j < 4; j++) b0[j] = Bs[kk][tx * 4 + j];
#pragma unroll
      for (int i = 0; i < 4; i++)
#pragma unroll
        for (int j = 0; j < 4; j++) acc[i][j] += a0[i] * b0[j];
    }
    __syncthreads();
  }
  float* __restrict__ Cp = y + (size_t)b * OCH * NSP;
#pragma unroll
  for (int i = 0; i < 4; i++) {
    int r = row0 + ty * 4 + i;
    float bias = bst[r];
#pragma unroll
    for (int j = 0; j < 4; j++)
      Cp[(size_t)r * NSP + (col0 + tx * 4 + j)] = acc[i][j] + bias;
  }
}

// ---------------------------------------------------------------------------
__global__ __launch_bounds__(256) void bn_stats(
    const float* __restrict__ y,
    const float* __restrict__ qs_, const float* __restrict__ qb_,
    const float* __restrict__ ks_, const float* __restrict__ kb_,
    const float* __restrict__ vs_, const float* __restrict__ vb_,
    float* __restrict__ chanA, float* __restrict__ chanB) {
  const int ch = blockIdx.x;
  const int tid = threadIdx.x;
  float s = 0.f, s2 = 0.f;
  for (int b = 0; b < BB; b++) {
    const float* p = y + ((size_t)b * OCH + ch) * NSP;
    for (int n = tid; n < NSP; n += 256) {
      float v = p[n];
      s += v;
      s2 += v * v;
    }
  }
  __shared__ float sb[8];
#pragma unroll
  for (int off = 32; off > 0; off >>= 1) {
    s += __shfl_down(s, off);
    s2 += __shfl_down(s2, off);
  }
  int lane = tid & 63, wid = tid >> 6;
  if (lane == 0) { sb[wid] = s; sb[4 + wid] = s2; }
  __syncthreads();
  if (tid == 0) {
    float ts  = sb[0] + sb[1] + sb[2] + sb[3];
    float ts2 = sb[4] + sb[5] + sb[6] + sb[7];
    const float inv = 1.f / (float)(BB * NSP);
    float mean = ts * inv;
    float var  = ts2 * inv - mean * mean;
    float scale, bias;
    if (ch < 64)       { scale = qs_[ch];       bias = qb_[ch]; }
    else if (ch < 128) { scale = ks_[ch - 64];  bias = kb_[ch - 64]; }
    else               { scale = vs_[ch - 128]; bias = vb_[ch - 128]; }
    float a = scale * rsqrtf(var + 1e-5f);
    chanA[ch] = a;
    chanB[ch] = bias - mean * a;
  }
}

// y = relu(a*y+b) in-place; also emit bf16 copy of v channels
__global__ __launch_bounds__(256) void bn_apply(
    float* __restrict__ y, const float* __restrict__ chanA,
    const float* __restrict__ chanB, unsigned short* __restrict__ vb16) {
  size_t i4 = (size_t)blockIdx.x * 256 + threadIdx.x;
  size_t i = i4 * 4;
  int n  = (int)(i % NSP);
  int ch = (int)((i / NSP) % OCH);
  int b  = (int)(i / ((size_t)NSP * OCH));
  float a = chanA[ch], bo = chanB[ch];
  float4 v = *(const float4*)(y + i);
  v.x = fmaxf(0.f, a * v.x + bo);
  v.y = fmaxf(0.f, a * v.y + bo);
  v.z = fmaxf(0.f, a * v.z + bo);
  v.w = fmaxf(0.f, a * v.w + bo);
  *(float4*)(y + i) = v;
  if (ch >= 128) {
    ushort4 h;
    h.x = f2bf(v.x); h.y = f2bf(v.y); h.z = f2bf(v.z); h.w = f2bf(v.w);
    *(ushort4*)&vb16[((size_t)(b * CIN + (ch - 128))) * NSP + n] = h;
  }
}

// qTb[b][i][d] = bf16(q[b][d][i])
__global__ __launch_bounds__(256) void qt_kernel(
    const float* __restrict__ qkv, unsigned short* __restrict__ qTb) {
  int idx = blockIdx.x * 256 + threadIdx.x;  // B*NSP*64
  int d = idx & 63;
  int rest = idx >> 6;
  int i = rest % NSP;
  int b = rest / NSP;
  qTb[idx] = f2bf(qkv[((size_t)b * OCH + d) * NSP + i]);
}

// ---------------------------------------------------------------------------
// energy: E[b,i,j] = sum_d q[b,d,i]*k[b,d,j]
__global__ __launch_bounds__(256) void energy_gemm(
    const float* __restrict__ qkv, float* __restrict__ E) {
  __shared__ float As[16][68];
  __shared__ float Bs[16][68];
  const int b = blockIdx.z;
  const int row0 = blockIdx.y * 64;
  const int col0 = blockIdx.x * 64;
  const float* __restrict__ q = qkv + (size_t)b * OCH * NSP;
  const float* __restrict__ k = q + (size_t)64 * NSP;
  const int tid = threadIdx.x;
  const int tx = tid & 15, ty = tid >> 4;
  float acc[4][4] = {{0.f, 0.f, 0.f, 0.f}};
  for (int k0 = 0; k0 < DKD; k0 += 16) {
#pragma unroll
    for (int l = 0; l < 4; l++) {
      int idx = tid + l * 256;
      int kk = idx >> 6, m = idx & 63;
      As[kk][m] = q[(size_t)(k0 + kk) * NSP + row0 + m];
      Bs[kk][m] = k[(size_t)(k0 + kk) * NSP + col0 + m];
    }
    __syncthreads();
#pragma unroll
    for (int kk = 0; kk < 16; kk++) {
      float a0[4], b0[4];
#pragma unroll
      for (int i = 0; i < 4; i++) a0[i] = As[kk][ty * 4 + i];
#pragma unroll
      for (int j = 0; j < 4; j++) b0[j] = Bs[kk][tx * 4 + j];
#pragma unroll
      for (int i = 0; i < 4; i++)
#pragma unroll
        for (int j = 0; j < 4; j++) acc[i][j] += a0[i] * b0[j];
    }
    __syncthreads();
  }
  float* __restrict__ Ep = E + (size_t)b * NSP * NSP;
#pragma unroll
  for (int i = 0; i < 4; i++)
#pragma unroll
    for (int j = 0; j < 4; j++)
      Ep[(size_t)(row0 + ty * 4 + i) * NSP + (col0 + tx * 4 + j)] = acc[i][j];
}

// softmax over last axis; reads fp32 row, writes bf16 row IN PLACE
// (row i's bf16 data occupies the first NSP shorts of the fp32 row slot;
//  effective bf16 row stride = 2*NSP shorts)
__global__ __launch_bounds__(256) void softmax_rows(float* __restrict__ E) {
  const size_t row = blockIdx.x;
  float* p = E + row * NSP;
  const int tid = threadIdx.x;
  float v[9];
  float mx = -1e30f;
#pragma unroll
  for (int t = 0; t < 9; t++) {
    v[t] = p[tid + t * 256];
    mx = fmaxf(mx, v[t]);
  }
  __shared__ float sb[8];
#pragma unroll
  for (int off = 32; off > 0; off >>= 1) mx = fmaxf(mx, __shfl_down(mx, off));
  int lane = tid & 63, wid = tid >> 6;
  if (lane == 0) sb[wid] = mx;
  __syncthreads();
  mx = fmaxf(fmaxf(sb[0], sb[1]), fmaxf(sb[2], sb[3]));
  float s = 0.f;
#pragma unroll
  for (int t = 0; t < 9; t++) {
    v[t] = __expf(v[t] - mx);
    s += v[t];
  }
#pragma unroll
  for (int off = 32; off > 0; off >>= 1) s += __shfl_down(s, off);
  if (lane == 0) sb[4 + wid] = s;
  __syncthreads();
  float inv = 1.f / (sb[4] + sb[5] + sb[6] + sb[7]);
  unsigned short* pb = (unsigned short*)p;
#pragma unroll
  for (int t = 0; t < 9; t++) pb[tid + t * 256] = f2bf(v[t] * inv);
}

// ---------------------------------------------------------------------------
// fp32 NT gemm (kept for the small rel-position GEMMs)
__global__ __launch_bounds__(256) void nt_gemm(
    const float* __restrict__ A, const float* __restrict__ B,
    float* __restrict__ C, int K, int lda, int ldb, int ldc,
    size_t strA, size_t strB, size_t strC) {
  __shared__ float As[16][68];
  __shared__ float Bs[16][68];
  const int b = blockIdx.z;
  const int row0 = blockIdx.y * 64;
  const int col0 = blockIdx.x * 64;
  const float* __restrict__ Ap = A + (size_t)b * strA;
  const float* __restrict__ Bp = B + (size_t)b * strB;
  const int tid = threadIdx.x;
  const int tx = tid & 15, ty = tid >> 4;
  float acc[4][4] = {{0.f, 0.f, 0.f, 0.f}};
  for (int k0 = 0; k0 < K; k0 += 16) {
#pragma unroll
    for (int l = 0; l < 4; l++) {
      int idx = tid + l * 256;
      int m = idx >> 4, kk = idx & 15;
      As[kk][m] = Ap[(size_t)(row0 + m) * lda + (k0 + kk)];
      Bs[kk][m] = Bp[(size_t)(col0 + m) * ldb + (k0 + kk)];
    }
    __syncthreads();
#pragma unroll
    for (int kk = 0; kk < 16; kk++) {
      float a0[4], b0[4];
#pragma unroll
      for (int i = 0; i < 4; i++) a0[i] = As[kk][ty * 4 + i];
#pragma unroll
      for (int j = 0; j < 4; j++) b0[j] = Bs[kk][tx * 4 + j];
#pragma unroll
      for (int i = 0; i < 4; i++)
#pragma unroll
        for (int j = 0; j < 4; j++) acc[i][j] += a0[i] * b0[j];
    }
    __syncthreads();
  }
  float* __restrict__ Cp = C + (size_t)b * strC;
#pragma unroll
  for (int i = 0; i < 4; i++)
#pragma unroll
    for (int j = 0; j < 4; j++)
      Cp[(size_t)(row0 + ty * 4 + i) * ldc + (col0 + tx * 4 + j)] = acc[i][j];
}

__global__ __launch_bounds__(256) void qsum_kernel(
    const float* __restrict__ qkv, float* __restrict__ qs) {
  int bd = blockIdx.x;
  int b = bd >> 6, d = bd & 63;
  const float* p = qkv + ((size_t)b * OCH + d) * NSP;
  float s = 0.f;
  for (int n = threadIdx.x; n < NSP; n += 256) s += p[n];
  __shared__ float sb[4];
#pragma unroll
  for (int off = 32; off > 0; off >>= 1) s += __shfl_down(s, off);
  int lane = threadIdx.x & 63, wid = threadIdx.x >> 6;
  if (lane == 0) sb[wid] = s;
  __syncthreads();
  if (threadIdx.x == 0) qs[bd] = sb[0] + sb[1] + sb[2] + sb[3];
}

__global__ __launch_bounds__(64) void rel_stats(
    const float* __restrict__ Uh, const float* __restrict__ Uw,
    const float* __restrict__ Gq, const float* __restrict__ qs,
    const float* __restrict__ bnr_s, const float* __restrict__ bnr_b,
    const float* __restrict__ bnc_s, const float* __restrict__ bnc_b,
    float* __restrict__ gh, float* __restrict__ gw, float* __restrict__ offc) {
  const int c = blockIdx.x;
  const int d = threadIdx.x;
  __shared__ float su[2][64];
  float s1h = 0.f, s2h = 0.f, s1w = 0.f, s2w = 0.f;
  for (int b = 0; b < BB; b++) {
    float uh = Uh[((size_t)b * CIN + c) * 64 + d];
    float uw = Uw[((size_t)b * CIN + c) * 64 + d];
    __syncthreads();
    su[0][d] = uh;
    su[1][d] = uw;
    __syncthreads();
    const float* G = Gq + (size_t)b * 4096 + d * 64;
    float th = 0.f, tw = 0.f;
    for (int e = 0; e < 64; e++) {
      float g = G[e];
      th += g * su[0][e];
      tw += g * su[1][e];
    }
    float qsd = qs[b * 64 + d];
    s1h += uh * qsd;
    s2h += uh * th;
    s1w += uw * qsd;
    s2w += uw * tw;
  }
#pragma unroll
  for (int off = 32; off > 0; off >>= 1) {
    s1h += __shfl_down(s1h, off);
    s2h += __shfl_down(s2h, off);
    s1w += __shfl_down(s1w, off);
    s2w += __shfl_down(s2w, off);
  }
  if (d == 0) {
    const float inv = 1.f / (float)(BB * NSP);
    float mh = s1h * inv, vh = s2h * inv - mh * mh;
    float mw = s1w * inv, vw = s2w * inv - mw * mw;
    float gch = bnr_s[c] * rsqrtf(vh + 1e-5f);
    float gcw = bnc_s[c] * rsqrtf(vw + 1e-5f);
    gh[c] = gch;
    gw[c] = gcw;
    offc[c] = (bnr_b[c] - mh * gch) + (bnc_b[c] - mw * gcw);
  }
}

// Ucb[b][c][d] = bf16( Uh*gh + Uw*gw )
__global__ __launch_bounds__(256) void combine_u(
    const float* __restrict__ Uh, const float* __restrict__ Uw,
    const float* __restrict__ gh, const float* __restrict__ gw,
    unsigned short* __restrict__ Ucb) {
  int idx = blockIdx.x * 256 + threadIdx.x;  // B*512*64
  int d = idx & 63;
  int c = (idx >> 6) & 511;
  size_t src = (size_t)idx;                  // same [b][c][d] layout
  (void)d;
  Ucb[idx] = f2bf(Uh[src] * gh[c] + Uw[src] * gw[c]);
}

// ---------------------------------------------------------------------------
// Fused MFMA kernel: dst[c,i] = gamma*( sum_j vb[c,j]*att[i,j]
//                                     + sum_d Ucb[c,d]*qT[i,d] + offc[c] ) + x[c,i]
// 128x128 tile, BK=64, 4 waves (2x2), mfma 16x16x32 bf16, global_load_lds x16
#define TM 128
#define TN 128
#define BK 64

__global__ __launch_bounds__(256) void attn_fused_gemm(
    const unsigned short* __restrict__ vb,    // [B][512][2304]
    const unsigned short* __restrict__ attb,  // bf16 rows, stride 2*NSP shorts
    const unsigned short* __restrict__ Ucb,   // [B][512][64]
    const unsigned short* __restrict__ qTb,   // [B][2304][64]
    const float* __restrict__ offc,
    const float* __restrict__ gammap,
    const float* __restrict__ x,
    float* __restrict__ dst) {
  __shared__ unsigned short As[TM * BK];   // 16 KB
  __shared__ unsigned short Bs[TN * BK];   // 16 KB
  const int b  = blockIdx.z;
  const int c0 = blockIdx.y * TM;
  const int i0 = blockIdx.x * TN;
  const int tid  = threadIdx.x;
  const int lane = tid & 63;
  const int w    = tid >> 6;
  const int wr = w >> 1, wc = w & 1;
  const unsigned short* vA = vb + (size_t)b * CIN * NSP;
  const unsigned short* aB = attb + (size_t)b * NSP * (2 * NSP);

  f32x4 acc[4][4] = {};

  const int colb = (lane & 7) * 8;        // k-col within tile for staging
  const int rsub = lane >> 3;             // 0..7

  for (int j0 = 0; j0 < NSP; j0 += BK) {
#pragma unroll
    for (int cc = 0; cc < 4; cc++) {
      int base = w * 2048 + cc * 512;          // lds element base (wave-uniform)
      int row = (base >> 6) + rsub;            // + lane*8 spread: 8 rows/call
      const unsigned short* gA = vA + (size_t)(c0 + row) * NSP + j0 + colb;
      __builtin_amdgcn_global_load_lds(
          (const __attribute__((address_space(1))) void*)gA,
          (__attribute__((address_space(3))) void*)&As[base], 16, 0, 0);
      const unsigned short* gB = aB + (size_t)(i0 + row) * (2 * NSP) + j0 + colb;
      __builtin_amdgcn_global_load_lds(
          (const __attribute__((address_space(1))) void*)gB,
          (__attribute__((address_space(3))) void*)&Bs[base], 16, 0, 0);
    }
    __syncthreads();
#pragma unroll
    for (int kk = 0; kk < 2; kk++) {
      bf16x8 af[4], bfr[4];
      int kcol = kk * 32 + (lane >> 4) * 8;
#pragma unroll
      for (int m = 0; m < 4; m++) {
        int row = wr * 64 + m * 16 + (lane & 15);
        af[m] = *(const bf16x8*)&As[row * BK + kcol];
      }
#pragma unroll
      for (int n = 0; n < 4; n++) {
        int row = wc * 64 + n * 16 + (lane & 15);
        bfr[n] = *(const bf16x8*)&Bs[row * BK + kcol];
      }
#pragma unroll
      for (int m = 0; m < 4; m++)
#pragma unroll
        for (int n = 0; n < 4; n++)
          acc[m][n] = __builtin_amdgcn_mfma_f32_16x16x32_bf16(
              af[m], bfr[n], acc[m][n], 0, 0, 0);
    }
    __syncthreads();
  }

  // extra K=64 tile: rel-position rank-64 term
  {
    const unsigned short* A2 = Ucb + (size_t)b * CIN * 64;
    const unsigned short* B2 = qTb + (size_t)b * NSP * 64;
#pragma unroll
    for (int cc = 0; cc < 4; cc++) {
      int base = w * 2048 + cc * 512;
      int row = (base >> 6) + rsub;
      const unsigned short* gA = A2 + (size_t)(c0 + row) * 64 + colb;
      __builtin_amdgcn_global_load_lds(
          (const __attribute__((address_space(1))) void*)gA,
          (__attribute__((address_space(3))) void*)&As[base], 16, 0, 0);
      const unsigned short* gB = B2 + (size_t)(i0 + row) * 64 + colb;
      __builtin_amdgcn_global_load_lds(
          (const __attribute__((address_space(1))) void*)gB,
          (__attribute__((address_space(3))) void*)&Bs[base], 16, 0, 0);
    }
    __syncthreads();
#pragma unroll
    for (int kk = 0; kk < 2; kk++) {
      bf16x8 af[4], bfr[4];
      int kcol = kk * 32 + (lane >> 4) * 8;
#pragma unroll
      for (int m = 0; m < 4; m++) {
        int row = wr * 64 + m * 16 + (lane & 15);
        af[m] = *(const bf16x8*)&As[row * BK + kcol];
      }
#pragma unroll
      for (int n = 0; n < 4; n++) {
        int row = wc * 64 + n * 16 + (lane & 15);
        bfr[n] = *(const bf16x8*)&Bs[row * BK + kcol];
      }
#pragma unroll
      for (int m = 0; m < 4; m++)
#pragma unroll
        for (int n = 0; n < 4; n++)
          acc[m][n] = __builtin_amdgcn_mfma_f32_16x16x32_bf16(
              af[m], bfr[n], acc[m][n], 0, 0, 0);
    }
  }

  // epilogue: dst = gamma*(acc + offc) + x
  const float gmm = gammap[0];
  const float* xp = x + (size_t)b * CIN * NSP;
  float* dp = dst + (size_t)b * CIN * NSP;
#pragma unroll
  for (int m = 0; m < 4; m++) {
#pragma unroll
    for (int r = 0; r < 4; r++) {
      int c = c0 + wr * 64 + m * 16 + (lane >> 4) * 4 + r;
      float off = offc[c];
#pragma unroll
      for (int n = 0; n < 4; n++) {
        int i = i0 + wc * 64 + n * 16 + (lane & 15);
        size_t o = (size_t)c * NSP + i;
        dp[o] = gmm * (acc[m][n][r] + off) + xp[o];
      }
    }
  }
}

// ---------------------------------------------------------------------------
extern "C" void kernel_launch(void* const* d_in, const int* in_sizes, int n_in,
                              void* d_out, int out_size, void* d_ws, size_t ws_size,
                              hipStream_t stream) {
  const float* x        = (const float*)d_in[0];
  const float* Wq       = (const float*)d_in[1];
  const float* bq       = (const float*)d_in[2];
  const float* q_scale  = (const float*)d_in[3];
  const float* q_bias   = (const float*)d_in[4];
  const float* Wk       = (const float*)d_in[5];
  const float* bk       = (const float*)d_in[6];
  const float* k_scale  = (const float*)d_in[7];
  const float* k_bias   = (const float*)d_in[8];
  const float* Wv       = (const float*)d_in[9];
  const float* bv       = (const float*)d_in[10];
  const float* v_scale  = (const float*)d_in[11];
  const float* v_bias   = (const float*)d_in[12];
  const float* rel_rows = (const float*)d_in[13];
  const float* rel_cols = (const float*)d_in[14];
  const float* bnr_s    = (const float*)d_in[15];
  const float* bnr_b    = (const float*)d_in[16];
  const float* bnc_s    = (const float*)d_in[17];
  const float* bnc_b    = (const float*)d_in[18];
  const float* gamma    = (const float*)d_in[19];
  float* dst = (float*)d_out;

  float* ws = (float*)d_ws;
  size_t o = 0;
  float* Wst    = ws + o; o += (size_t)OCH * CIN;
  float* bst    = ws + o; o += 1024;
  float* chanA  = ws + o; o += 1024;
  float* chanB  = ws + o; o += 1024;
  float* PhT    = ws + o; o += (size_t)64 * NSP;
  float* PwT    = ws + o; o += (size_t)64 * NSP;
  float* qkv    = ws + o; o += (size_t)BB * OCH * NSP;    // 11.8M
  float* energy = ws + o; o += (size_t)BB * NSP * NSP;    // 42.5M (fp32 -> bf16 in place)
  float* Uh     = ws + o; o += (size_t)BB * CIN * 64;
  float* Uw     = ws + o; o += (size_t)BB * CIN * 64;
  float* Gq     = ws + o; o += (size_t)BB * 64 * 64;
  float* qs     = ws + o; o += 1024;
  float* gh     = ws + o; o += 1024;
  float* gw     = ws + o; o += 1024;
  float* offc   = ws + o; o += 1024;
  unsigned short* vb16 = (unsigned short*)(ws + o); o += (size_t)BB * CIN * NSP / 2;  // bf16 v
  unsigned short* qTb  = (unsigned short*)(ws + o); o += (size_t)BB * NSP * 64 / 2;   // bf16 q^T
  unsigned short* Ucb  = (unsigned short*)(ws + o); o += (size_t)BB * CIN * 64 / 2;   // bf16 Uc

  // prep
  stack_w<<<(OCH * CIN) / 256, 256, 0, stream>>>(Wq, bq, Wk, bk, Wv, bv, Wst, bst);
  prep_pt<<<(64 * NSP) / 256, 256, 0, stream>>>(rel_rows, rel_cols, PhT, PwT);

  // qkv projection + BN + relu (+ bf16 v emit)
  proj_gemm<<<dim3(NSP / 64, OCH / 64, BB), 256, 0, stream>>>(Wst, bst, x, qkv);
  bn_stats<<<OCH, 256, 0, stream>>>(qkv, q_scale, q_bias, k_scale, k_bias,
                                    v_scale, v_bias, chanA, chanB);
  bn_apply<<<(int)((size_t)BB * OCH * NSP / 4 / 256), 256, 0, stream>>>(qkv, chanA, chanB, vb16);
  qt_kernel<<<(BB * NSP * 64) / 256, 256, 0, stream>>>(qkv, qTb);

  // attention scores
  energy_gemm<<<dim3(NSP / 64, NSP / 64, BB), 256, 0, stream>>>(qkv, energy);
  softmax_rows<<<BB * NSP, 256, 0, stream>>>(energy);

  // rel-position small GEMMs (fp32): Uh = v@PhT^T, Uw, Gq = q q^T
  nt_gemm<<<dim3(1, CIN / 64, BB), 256, 0, stream>>>(
      qkv + (size_t)128 * NSP, PhT, Uh, NSP, NSP, NSP, 64,
      (size_t)OCH * NSP, 0, (size_t)CIN * 64);
  nt_gemm<<<dim3(1, CIN / 64, BB), 256, 0, stream>>>(
      qkv + (size_t)128 * NSP, PwT, Uw, NSP, NSP, NSP, 64,
      (size_t)OCH * NSP, 0, (size_t)CIN * 64);
  nt_gemm<<<dim3(1, 1, BB), 256, 0, stream>>>(
      qkv, qkv, Gq, NSP, NSP, NSP, 64,
      (size_t)OCH * NSP, (size_t)OCH * NSP, (size_t)64 * 64);
  qsum_kernel<<<BB * 64, 256, 0, stream>>>(qkv, qs);
  rel_stats<<<CIN, 64, 0, stream>>>(Uh, Uw, Gq, qs, bnr_s, bnr_b, bnc_s, bnc_b,
                                    gh, gw, offc);
  combine_u<<<(BB * CIN * 64) / 256, 256, 0, stream>>>(Uh, Uw, gh, gw, Ucb);

  // fused MFMA: V*A^T + Uc*q^T + offc, *gamma, +x  -> dst
  attn_fused_gemm<<<dim3(NSP / TN, CIN / TM, BB), 256, 0, stream>>>(
      vb16, (const unsigned short*)energy, Ucb, qTb, offc, gamma, x, dst);
}

// Round 3
// 433.900 us; speedup vs baseline: 3.0058x; 1.8929x over previous
//
#include <hip/hip_runtime.h>
#include <math.h>

#define BB   8
#define CIN  512
#define NSP  2304
#define OCH  640   // 64(q)+64(k)+512(v)
#define LL   48

typedef __attribute__((ext_vector_type(8))) short bf16x8;
typedef __attribute__((ext_vector_type(4))) float f32x4;

__device__ inline unsigned short f2bf(float f) {
  unsigned int u = __float_as_uint(f);
  unsigned int r = (u + 0x7fffu + ((u >> 16) & 1u)) >> 16;   // RNE
  return (unsigned short)r;
}
__device__ inline float bf2f(unsigned short h) {
  return __uint_as_float(((unsigned int)h) << 16);
}

// stage a 128-row x 64-col bf16 tile (row stride LD elements) into LDS linear
// [128][64]; requires in-scope: w (wave id 0..3), colb, rsub
#define STAGE128x64(GP, LD, LDSN)                                              \
  {                                                                            \
    const unsigned short* gsrc_ = (GP);                                        \
    _Pragma("unroll") for (int cc_ = 0; cc_ < 4; cc_++) {                      \
      int base_ = w * 2048 + cc_ * 512;                                        \
      int row_ = w * 32 + cc_ * 8 + rsub;                                      \
      __builtin_amdgcn_global_load_lds(                                        \
          (const __attribute__((address_space(1))) void*)(gsrc_ +              \
              (size_t)row_ * (LD) + colb),                                     \
          (__attribute__((address_space(3))) void*)&LDSN[base_], 16, 0, 0);    \
    }                                                                          \
  }

// 128x128 output tile, one K=64 step from As/Bs; needs lane, wr, wc, acc
#define MFMA128x128x64()                                                       \
  _Pragma("unroll") for (int kk_ = 0; kk_ < 2; kk_++) {                        \
    bf16x8 af_[4], bf_[4];                                                     \
    int kcol_ = kk_ * 32 + (lane >> 4) * 8;                                    \
    _Pragma("unroll") for (int m_ = 0; m_ < 4; m_++)                           \
      af_[m_] = *(const bf16x8*)&As[(wr * 64 + m_ * 16 + (lane & 15)) * 64 + kcol_]; \
    _Pragma("unroll") for (int n_ = 0; n_ < 4; n_++)                           \
      bf_[n_] = *(const bf16x8*)&Bs[(wc * 64 + n_ * 16 + (lane & 15)) * 64 + kcol_]; \
    _Pragma("unroll") for (int m_ = 0; m_ < 4; m_++)                           \
      _Pragma("unroll") for (int n_ = 0; n_ < 4; n_++)                         \
        acc[m_][n_] = __builtin_amdgcn_mfma_f32_16x16x32_bf16(                 \
            af_[m_], bf_[n_], acc[m_][n_], 0, 0, 0);                           \
  }

#define MFMA_PROLOG()                                                          \
  const int tid = threadIdx.x;                                                 \
  const int lane = tid & 63;                                                   \
  const int w = tid >> 6;                                                      \
  const int wr = w >> 1, wc = w & 1;                                           \
  const int colb = (lane & 7) * 8;                                             \
  const int rsub = lane >> 3;                                                  \
  f32x4 acc[4][4] = {};                                                        \
  (void)colb; (void)rsub;

// ---------------------------------------------------------------------------
// stack Wq/Wk/Wv -> bf16 (640 x 512) + fp32 stacked bias
__global__ __launch_bounds__(256) void stack_wb(
    const float* __restrict__ Wq, const float* __restrict__ bq,
    const float* __restrict__ Wk, const float* __restrict__ bk,
    const float* __restrict__ Wv, const float* __restrict__ bv,
    unsigned short* __restrict__ Wstb, float* __restrict__ bst) {
  int idx = blockIdx.x * 256 + threadIdx.x;   // 640*512
  int row = idx >> 9;
  float val;
  if (row < 64)       val = Wq[idx];
  else if (row < 128) val = Wk[idx - (64 << 9)];
  else                val = Wv[idx - (128 << 9)];
  Wstb[idx] = f2bf(val);
  if (idx < OCH) {
    float bval;
    if (idx < 64)       bval = bq[idx];
    else if (idx < 128) bval = bk[idx - 64];
    else                bval = bv[idx - 128];
    bst[idx] = bval;
  }
}

// Pcatb[dd][n] bf16: dd<64 -> rel_rows[shift(n)][dd], else rel_cols[shift(n)][dd-64]
__global__ __launch_bounds__(256) void prep_pcat(
    const float* __restrict__ rel_rows, const float* __restrict__ rel_cols,
    unsigned short* __restrict__ Pcatb) {
  int idx = blockIdx.x * 256 + threadIdx.x;   // 128*2304
  int dd = idx / NSP;
  int n = idx - dd * NSP;
  int xr = n / LL;
  int ic = n - xr * LL;
  int shift = ic - xr + (LL - 1);
  float val = (dd < 64) ? rel_rows[shift * 64 + dd] : rel_cols[shift * 64 + (dd - 64)];
  Pcatb[idx] = f2bf(val);
}

// x [b][c][n] fp32 -> xTb [b][n][c] bf16, 64x64 LDS tiles
__global__ __launch_bounds__(256) void transpose_x(
    const float* __restrict__ x, unsigned short* __restrict__ xTb) {
  __shared__ float t[64][65];
  const int n0 = blockIdx.x * 64;
  const int c0 = blockIdx.y * 64;
  const int b = blockIdx.z;
  const int j = threadIdx.x & 63;
  const int g = threadIdx.x >> 6;
  const float* xp = x + (size_t)b * CIN * NSP;
#pragma unroll
  for (int i = 0; i < 16; i++) {
    int cl = g * 16 + i;
    t[cl][j] = xp[(size_t)(c0 + cl) * NSP + n0 + j];
  }
  __syncthreads();
  unsigned short* op = xTb + (size_t)b * NSP * CIN;
#pragma unroll
  for (int i = 0; i < 16; i++) {
    int nl = g * 16 + i;
    op[(size_t)(n0 + nl) * CIN + c0 + j] = f2bf(t[j][nl]);
  }
}

// ---------------------------------------------------------------------------
// proj: y[b,o,n] = sum_c Wstb[o,c]*xTb[b,n,c] + bst[o]   (fp32 out)
__global__ __launch_bounds__(256) void proj_mfma(
    const unsigned short* __restrict__ Wstb, const float* __restrict__ bst,
    const unsigned short* __restrict__ xTb, float* __restrict__ y) {
  __shared__ unsigned short As[128 * 64];
  __shared__ unsigned short Bs[128 * 64];
  const int b = blockIdx.z;
  const int r0 = blockIdx.y * 128;   // o
  const int n0 = blockIdx.x * 128;   // n
  MFMA_PROLOG();
  const unsigned short* A = Wstb + (size_t)r0 * CIN;
  const unsigned short* B = xTb + (size_t)b * NSP * CIN + (size_t)n0 * CIN;
  for (int k0 = 0; k0 < CIN; k0 += 64) {
    STAGE128x64(A + k0, CIN, As);
    STAGE128x64(B + k0, CIN, Bs);
    __syncthreads();
    MFMA128x128x64();
    __syncthreads();
  }
  float* yp = y + (size_t)b * OCH * NSP;
#pragma unroll
  for (int m = 0; m < 4; m++) {
#pragma unroll
    for (int r = 0; r < 4; r++) {
      int row = r0 + wr * 64 + m * 16 + (lane >> 4) * 4 + r;
      float bias = bst[row];
#pragma unroll
      for (int n = 0; n < 4; n++) {
        int col = n0 + wc * 64 + n * 16 + (lane & 15);
        yp[(size_t)row * NSP + col] = acc[m][n][r] + bias;
      }
    }
  }
}

// ---------------------------------------------------------------------------
__global__ __launch_bounds__(256) void bn_stats(
    const float* __restrict__ y,
    const float* __restrict__ qs_, const float* __restrict__ qb_,
    const float* __restrict__ ks_, const float* __restrict__ kb_,
    const float* __restrict__ vs_, const float* __restrict__ vb_,
    float* __restrict__ chanA, float* __restrict__ chanB) {
  const int ch = blockIdx.x;
  const int tid = threadIdx.x;
  float s = 0.f, s2 = 0.f;
  for (int b = 0; b < BB; b++) {
    const float* p = y + ((size_t)b * OCH + ch) * NSP;
    for (int n = tid; n < NSP; n += 256) {
      float v = p[n];
      s += v;
      s2 += v * v;
    }
  }
  __shared__ float sb[8];
#pragma unroll
  for (int off = 32; off > 0; off >>= 1) {
    s += __shfl_down(s, off);
    s2 += __shfl_down(s2, off);
  }
  int lane = tid & 63, wid = tid >> 6;
  if (lane == 0) { sb[wid] = s; sb[4 + wid] = s2; }
  __syncthreads();
  if (tid == 0) {
    float ts  = sb[0] + sb[1] + sb[2] + sb[3];
    float ts2 = sb[4] + sb[5] + sb[6] + sb[7];
    const float inv = 1.f / (float)(BB * NSP);
    float mean = ts * inv;
    float var  = ts2 * inv - mean * mean;
    float scale, bias;
    if (ch < 64)       { scale = qs_[ch];       bias = qb_[ch]; }
    else if (ch < 128) { scale = ks_[ch - 64];  bias = kb_[ch - 64]; }
    else               { scale = vs_[ch - 128]; bias = vb_[ch - 128]; }
    float a = scale * rsqrtf(var + 1e-5f);
    chanA[ch] = a;
    chanB[ch] = bias - mean * a;
  }
}

// y = relu(a*y+b) in-place; also emit bf16 copy of v channels
__global__ __launch_bounds__(256) void bn_apply(
    float* __restrict__ y, const float* __restrict__ chanA,
    const float* __restrict__ chanB, unsigned short* __restrict__ vb16) {
  size_t i4 = (size_t)blockIdx.x * 256 + threadIdx.x;
  size_t i = i4 * 4;
  int n  = (int)(i % NSP);
  int ch = (int)((i / NSP) % OCH);
  int b  = (int)(i / ((size_t)NSP * OCH));
  float a = chanA[ch], bo = chanB[ch];
  float4 v = *(const float4*)(y + i);
  v.x = fmaxf(0.f, a * v.x + bo);
  v.y = fmaxf(0.f, a * v.y + bo);
  v.z = fmaxf(0.f, a * v.z + bo);
  v.w = fmaxf(0.f, a * v.w + bo);
  *(float4*)(y + i) = v;
  if (ch >= 128) {
    ushort4 h;
    h.x = f2bf(v.x); h.y = f2bf(v.y); h.z = f2bf(v.z); h.w = f2bf(v.w);
    *(ushort4*)&vb16[((size_t)(b * CIN + (ch - 128))) * NSP + n] = h;
  }
}

// qTb[b][i][d], kTb[b][i][d] bf16 from post-BN q/k
__global__ __launch_bounds__(256) void qkt_kernel(
    const float* __restrict__ qkv, unsigned short* __restrict__ qTb,
    unsigned short* __restrict__ kTb) {
  int idx = blockIdx.x * 256 + threadIdx.x;  // B*NSP*64
  int d = idx & 63;
  int rest = idx >> 6;
  int i = rest % NSP;
  int b = rest / NSP;
  const float* qb = qkv + (size_t)b * OCH * NSP;
  qTb[idx] = f2bf(qb[(size_t)d * NSP + i]);
  kTb[idx] = f2bf(qb[(size_t)(64 + d) * NSP + i]);
}

// ---------------------------------------------------------------------------
// energy+exp: Pp[b,i,j] = bf16( exp( sum_d qT[i,d]*kT[j,d] ) )   (no max-sub;
// q,k>=0 post-relu bound energy to ~35 -> exp safely inside fp32/bf16 range)
__global__ __launch_bounds__(256) void energy_mfma(
    const unsigned short* __restrict__ qTb, const unsigned short* __restrict__ kTb,
    unsigned short* __restrict__ Pp) {
  __shared__ unsigned short As[128 * 64];
  __shared__ unsigned short Bs[128 * 64];
  const int b = blockIdx.z;
  const int i0 = blockIdx.y * 128;
  const int j0 = blockIdx.x * 128;
  MFMA_PROLOG();
  STAGE128x64(qTb + (size_t)b * NSP * 64 + (size_t)i0 * 64, 64, As);
  STAGE128x64(kTb + (size_t)b * NSP * 64 + (size_t)j0 * 64, 64, Bs);
  __syncthreads();
  MFMA128x128x64();
  unsigned short* pp = Pp + (size_t)b * NSP * NSP;
#pragma unroll
  for (int m = 0; m < 4; m++) {
#pragma unroll
    for (int r = 0; r < 4; r++) {
      int i = i0 + wr * 64 + m * 16 + (lane >> 4) * 4 + r;
#pragma unroll
      for (int n = 0; n < 4; n++) {
        int j = j0 + wc * 64 + n * 16 + (lane & 15);
        pp[(size_t)i * NSP + j] = f2bf(__expf(acc[m][n][r]));
      }
    }
  }
}

// rZ[b*NSP+i] = 1 / sum_j Pp[b,i,j]; one wave per row
__global__ __launch_bounds__(256) void zsum_kernel(
    const unsigned short* __restrict__ Pp, float* __restrict__ rZ) {
  int row = blockIdx.x * 4 + (threadIdx.x >> 6);
  int lane = threadIdx.x & 63;
  const ushort4* pr = (const ushort4*)(Pp + (size_t)row * NSP);
  float s = 0.f;
#pragma unroll
  for (int t = 0; t < 9; t++) {
    ushort4 u = pr[lane + t * 64];
    s += bf2f(u.x) + bf2f(u.y) + bf2f(u.z) + bf2f(u.w);
  }
#pragma unroll
  for (int off = 32; off > 0; off >>= 1) s += __shfl_down(s, off);
  if (lane == 0) rZ[row] = 1.f / s;
}

// ---------------------------------------------------------------------------
// Ucat[b][c][dd] = sum_n vb[b,c,n]*Pcatb[dd,n]   (dd<64: Ph term, >=64: Pw)
__global__ __launch_bounds__(256) void up_mfma(
    const unsigned short* __restrict__ vb, const unsigned short* __restrict__ Pcatb,
    float* __restrict__ Ucat) {
  __shared__ unsigned short As[128 * 64];
  __shared__ unsigned short Bs[128 * 64];
  const int b = blockIdx.z;
  const int c0 = blockIdx.y * 128;
  MFMA_PROLOG();
  const unsigned short* A = vb + (size_t)b * CIN * NSP + (size_t)c0 * NSP;
  for (int k0 = 0; k0 < NSP; k0 += 64) {
    STAGE128x64(A + k0, NSP, As);
    STAGE128x64(Pcatb + k0, NSP, Bs);
    __syncthreads();
    MFMA128x128x64();
    __syncthreads();
  }
  float* up = Ucat + (size_t)b * CIN * 128;
#pragma unroll
  for (int m = 0; m < 4; m++) {
#pragma unroll
    for (int r = 0; r < 4; r++) {
      int row = c0 + wr * 64 + m * 16 + (lane >> 4) * 4 + r;
#pragma unroll
      for (int n = 0; n < 4; n++) {
        int col = wc * 64 + n * 16 + (lane & 15);
        up[(size_t)row * 128 + col] = acc[m][n][r];
      }
    }
  }
}

// fp32 NT gemm kept for Gq = q q^T (64x64, K=NSP)
__global__ __launch_bounds__(256) void nt_gemm(
    const float* __restrict__ A, const float* __restrict__ B,
    float* __restrict__ C, int K, int lda, int ldb, int ldc,
    size_t strA, size_t strB, size_t strC) {
  __shared__ float As[16][68];
  __shared__ float Bs[16][68];
  const int b = blockIdx.z;
  const int row0 = blockIdx.y * 64;
  const int col0 = blockIdx.x * 64;
  const float* __restrict__ Ap = A + (size_t)b * strA;
  const float* __restrict__ Bp = B + (size_t)b * strB;
  const int tid = threadIdx.x;
  const int tx = tid & 15, ty = tid >> 4;
  float acc[4][4] = {{0.f, 0.f, 0.f, 0.f}};
  for (int k0 = 0; k0 < K; k0 += 16) {
#pragma unroll
    for (int l = 0; l < 4; l++) {
      int idx = tid + l * 256;
      int m = idx >> 4, kk = idx & 15;
      As[kk][m] = Ap[(size_t)(row0 + m) * lda + (k0 + kk)];
      Bs[kk][m] = Bp[(size_t)(col0 + m) * ldb + (k0 + kk)];
    }
    __syncthreads();
#pragma unroll
    for (int kk = 0; kk < 16; kk++) {
      float a0[4], b0[4];
#pragma unroll
      for (int i = 0; i < 4; i++) a0[i] = As[kk][ty * 4 + i];
#pragma unroll
      for (int j = 0; j < 4; j++) b0[j] = Bs[kk][tx * 4 + j];
#pragma unroll
      for (int i = 0; i < 4; i++)
#pragma unroll
        for (int j = 0; j < 4; j++) acc[i][j] += a0[i] * b0[j];
    }
    __syncthreads();
  }
  float* __restrict__ Cp = C + (size_t)b * strC;
#pragma unroll
  for (int i = 0; i < 4; i++)
#pragma unroll
    for (int j = 0; j < 4; j++)
      Cp[(size_t)(row0 + ty * 4 + i) * ldc + (col0 + tx * 4 + j)] = acc[i][j];
}

__global__ __launch_bounds__(256) void qsum_kernel(
    const float* __restrict__ qkv, float* __restrict__ qs) {
  int bd = blockIdx.x;
  int b = bd >> 6, d = bd & 63;
  const float* p = qkv + ((size_t)b * OCH + d) * NSP;
  float s = 0.f;
  for (int n = threadIdx.x; n < NSP; n += 256) s += p[n];
  __shared__ float sb[4];
#pragma unroll
  for (int off = 32; off > 0; off >>= 1) s += __shfl_down(s, off);
  int lane = threadIdx.x & 63, wid = threadIdx.x >> 6;
  if (lane == 0) sb[wid] = s;
  __syncthreads();
  if (threadIdx.x == 0) qs[bd] = sb[0] + sb[1] + sb[2] + sb[3];
}

// closed-form BN stats for Eh/Ew from Ucat (stride 128: [0:64]=h, [64:128]=w)
__global__ __launch_bounds__(64) void rel_stats(
    const float* __restrict__ Ucat, const float* __restrict__ Gq,
    const float* __restrict__ qs,
    const float* __restrict__ bnr_s, const float* __restrict__ bnr_b,
    const float* __restrict__ bnc_s, const float* __restrict__ bnc_b,
    float* __restrict__ gh, float* __restrict__ gw, float* __restrict__ offc) {
  const int c = blockIdx.x;
  const int d = threadIdx.x;
  __shared__ float su[2][64];
  float s1h = 0.f, s2h = 0.f, s1w = 0.f, s2w = 0.f;
  for (int b = 0; b < BB; b++) {
    size_t base = ((size_t)b * CIN + c) * 128;
    float uh = Ucat[base + d];
    float uw = Ucat[base + 64 + d];
    __syncthreads();
    su[0][d] = uh;
    su[1][d] = uw;
    __syncthreads();
    const float* G = Gq + (size_t)b * 4096 + d * 64;
    float th = 0.f, tw = 0.f;
    for (int e = 0; e < 64; e++) {
      float g = G[e];
      th += g * su[0][e];
      tw += g * su[1][e];
    }
    float qsd = qs[b * 64 + d];
    s1h += uh * qsd;
    s2h += uh * th;
    s1w += uw * qsd;
    s2w += uw * tw;
  }
#pragma unroll
  for (int off = 32; off > 0; off >>= 1) {
    s1h += __shfl_down(s1h, off);
    s2h += __shfl_down(s2h, off);
    s1w += __shfl_down(s1w, off);
    s2w += __shfl_down(s2w, off);
  }
  if (d == 0) {
    const float inv = 1.f / (float)(BB * NSP);
    float mh = s1h * inv, vh = s2h * inv - mh * mh;
    float mw = s1w * inv, vw = s2w * inv - mw * mw;
    float gch = bnr_s[c] * rsqrtf(vh + 1e-5f);
    float gcw = bnc_s[c] * rsqrtf(vw + 1e-5f);
    gh[c] = gch;
    gw[c] = gcw;
    offc[c] = (bnr_b[c] - mh * gch) + (bnc_b[c] - mw * gcw);
  }
}

// Ucb[b][c][d] = bf16( Ucat_h*gh + Ucat_w*gw )
__global__ __launch_bounds__(256) void combine_u(
    const float* __restrict__ Ucat, const float* __restrict__ gh,
    const float* __restrict__ gw, unsigned short* __restrict__ Ucb) {
  int idx = blockIdx.x * 256 + threadIdx.x;  // B*512*64
  int d = idx & 63;
  int c = (idx >> 6) & 511;
  int b = idx >> 15;
  size_t base = ((size_t)b * CIN + c) * 128;
  Ucb[idx] = f2bf(Ucat[base + d] * gh[c] + Ucat[base + 64 + d] * gw[c]);
}

// ---------------------------------------------------------------------------
// fused: dst[c,i] = gamma*( rZ[i]*sum_j vb[c,j]*Pp[i,j]
//                         + sum_d Ucb[c,d]*qT[i,d] + offc[c] ) + x[c,i]
__global__ __launch_bounds__(256) void attn_fused_gemm(
    const unsigned short* __restrict__ vb,    // [B][512][2304]
    const unsigned short* __restrict__ Pp,    // [B][2304][2304] bf16
    const float* __restrict__ rZ,             // [B*2304]
    const unsigned short* __restrict__ Ucb,   // [B][512][64]
    const unsigned short* __restrict__ qTb,   // [B][2304][64]
    const float* __restrict__ offc,
    const float* __restrict__ gammap,
    const float* __restrict__ x,
    float* __restrict__ dst) {
  __shared__ unsigned short As[128 * 64];
  __shared__ unsigned short Bs[128 * 64];
  const int b  = blockIdx.z;
  const int c0 = blockIdx.y * 128;
  const int i0 = blockIdx.x * 128;
  MFMA_PROLOG();
  const unsigned short* A = vb + (size_t)b * CIN * NSP + (size_t)c0 * NSP;
  const unsigned short* B = Pp + (size_t)b * NSP * NSP + (size_t)i0 * NSP;

  for (int j0 = 0; j0 < NSP; j0 += 64) {
    STAGE128x64(A + j0, NSP, As);
    STAGE128x64(B + j0, NSP, Bs);
    __syncthreads();
    MFMA128x128x64();
    __syncthreads();
  }

  // per-column softmax normalization (applies only to the V*P' part)
#pragma unroll
  for (int n = 0; n < 4; n++) {
    float rz = rZ[(size_t)b * NSP + i0 + wc * 64 + n * 16 + (lane & 15)];
#pragma unroll
    for (int m = 0; m < 4; m++)
#pragma unroll
      for (int r = 0; r < 4; r++) acc[m][n][r] *= rz;
  }

  // rank-64 rel-position tile
  STAGE128x64(Ucb + (size_t)b * CIN * 64 + (size_t)c0 * 64, 64, As);
  STAGE128x64(qTb + (size_t)b * NSP * 64 + (size_t)i0 * 64, 64, Bs);
  __syncthreads();
  MFMA128x128x64();

  const float gmm = gammap[0];
  const float* xp = x + (size_t)b * CIN * NSP;
  float* dp = dst + (size_t)b * CIN * NSP;
#pragma unroll
  for (int m = 0; m < 4; m++) {
#pragma unroll
    for (int r = 0; r < 4; r++) {
      int c = c0 + wr * 64 + m * 16 + (lane >> 4) * 4 + r;
      float off = offc[c];
#pragma unroll
      for (int n = 0; n < 4; n++) {
        int i = i0 + wc * 64 + n * 16 + (lane & 15);
        size_t o = (size_t)c * NSP + i;
        dp[o] = gmm * (acc[m][n][r] + off) + xp[o];
      }
    }
  }
}

// ---------------------------------------------------------------------------
extern "C" void kernel_launch(void* const* d_in, const int* in_sizes, int n_in,
                              void* d_out, int out_size, void* d_ws, size_t ws_size,
                              hipStream_t stream) {
  const float* x        = (const float*)d_in[0];
  const float* Wq       = (const float*)d_in[1];
  const float* bq       = (const float*)d_in[2];
  const float* q_scale  = (const float*)d_in[3];
  const float* q_bias   = (const float*)d_in[4];
  const float* Wk       = (const float*)d_in[5];
  const float* bk       = (const float*)d_in[6];
  const float* k_scale  = (const float*)d_in[7];
  const float* k_bias   = (const float*)d_in[8];
  const float* Wv       = (const float*)d_in[9];
  const float* bv       = (const float*)d_in[10];
  const float* v_scale  = (const float*)d_in[11];
  const float* v_bias   = (const float*)d_in[12];
  const float* rel_rows = (const float*)d_in[13];
  const float* rel_cols = (const float*)d_in[14];
  const float* bnr_s    = (const float*)d_in[15];
  const float* bnr_b    = (const float*)d_in[16];
  const float* bnc_s    = (const float*)d_in[17];
  const float* bnc_b    = (const float*)d_in[18];
  const float* gamma    = (const float*)d_in[19];
  float* dst = (float*)d_out;

  float* ws = (float*)d_ws;
  size_t o = 0;
  unsigned short* Wstb = (unsigned short*)(ws + o); o += (size_t)OCH * CIN / 2;
  float* bst    = ws + o; o += 1024;
  float* chanA  = ws + o; o += 1024;
  float* chanB  = ws + o; o += 1024;
  unsigned short* Pcatb = (unsigned short*)(ws + o); o += (size_t)128 * NSP / 2;
  float* qkv    = ws + o; o += (size_t)BB * OCH * NSP;         // fp32 y
  unsigned short* xTb = (unsigned short*)(ws + o); o += (size_t)BB * NSP * CIN / 2;
  unsigned short* Pp  = (unsigned short*)(ws + o); o += (size_t)BB * NSP * NSP / 2;
  float* rZ     = ws + o; o += (size_t)BB * NSP;
  float* Ucat   = ws + o; o += (size_t)BB * CIN * 128;
  float* Gq     = ws + o; o += (size_t)BB * 64 * 64;
  float* qs     = ws + o; o += 1024;
  float* gh     = ws + o; o += 1024;
  float* gw     = ws + o; o += 1024;
  float* offc   = ws + o; o += 1024;
  unsigned short* vb16 = (unsigned short*)(ws + o); o += (size_t)BB * CIN * NSP / 2;
  unsigned short* qTb  = (unsigned short*)(ws + o); o += (size_t)BB * NSP * 64 / 2;
  unsigned short* kTb  = (unsigned short*)(ws + o); o += (size_t)BB * NSP * 64 / 2;
  unsigned short* Ucb  = (unsigned short*)(ws + o); o += (size_t)BB * CIN * 64 / 2;

  stack_wb<<<(OCH * CIN) / 256, 256, 0, stream>>>(Wq, bq, Wk, bk, Wv, bv, Wstb, bst);
  prep_pcat<<<(128 * NSP) / 256, 256, 0, stream>>>(rel_rows, rel_cols, Pcatb);
  transpose_x<<<dim3(NSP / 64, CIN / 64, BB), 256, 0, stream>>>(x, xTb);

  proj_mfma<<<dim3(NSP / 128, OCH / 128, BB), 256, 0, stream>>>(Wstb, bst, xTb, qkv);
  bn_stats<<<OCH, 256, 0, stream>>>(qkv, q_scale, q_bias, k_scale, k_bias,
                                    v_scale, v_bias, chanA, chanB);
  bn_apply<<<(int)((size_t)BB * OCH * NSP / 4 / 256), 256, 0, stream>>>(qkv, chanA, chanB, vb16);
  qkt_kernel<<<(BB * NSP * 64) / 256, 256, 0, stream>>>(qkv, qTb, kTb);

  energy_mfma<<<dim3(NSP / 128, NSP / 128, BB), 256, 0, stream>>>(qTb, kTb, Pp);
  zsum_kernel<<<BB * NSP / 4, 256, 0, stream>>>(Pp, rZ);

  up_mfma<<<dim3(1, CIN / 128, BB), 256, 0, stream>>>(vb16, Pcatb, Ucat);
  nt_gemm<<<dim3(1, 1, BB), 256, 0, stream>>>(
      qkv, qkv, Gq, NSP, NSP, NSP, 64,
      (size_t)OCH * NSP, (size_t)OCH * NSP, (size_t)64 * 64);
  qsum_kernel<<<BB * 64, 256, 0, stream>>>(qkv, qs);
  rel_stats<<<CIN, 64, 0, stream>>>(Ucat, Gq, qs, bnr_s, bnr_b, bnc_s, bnc_b,
                                    gh, gw, offc);
  combine_u<<<(BB * CIN * 64) / 256, 256, 0, stream>>>(Ucat, gh, gw, Ucb);

  attn_fused_gemm<<<dim3(NSP / 128, CIN / 128, BB), 256, 0, stream>>>(
      vb16, Pp, rZ, Ucb, qTb, offc, gamma, x, dst);
}

// Round 4
// 253.504 us; speedup vs baseline: 5.1448x; 1.7116x over previous
//
#include <hip/hip_runtime.h>
#include <math.h>

#define BB   8
#define CIN  512
#define NSP  2304
#define OCH  640   // 64(q)+64(k)+512(v)
#define LL   48

typedef __attribute__((ext_vector_type(8))) short bf16x8;
typedef __attribute__((ext_vector_type(4))) float f32x4;

__device__ inline unsigned short f2bf(float f) {
  unsigned int u = __float_as_uint(f);
  unsigned int r = (u + 0x7fffu + ((u >> 16) & 1u)) >> 16;   // RNE
  return (unsigned short)r;
}
__device__ inline float bf2f(unsigned short h) {
  return __uint_as_float(((unsigned int)h) << 16);
}

// stage a 128-row x 64-col bf16 tile (row stride LD elements) into LDS linear
// [128][64]; requires in-scope: w (wave id 0..3), colb, rsub
#define STAGE128x64(GP, LD, LDSN)                                              \
  {                                                                            \
    const unsigned short* gsrc_ = (GP);                                        \
    _Pragma("unroll") for (int cc_ = 0; cc_ < 4; cc_++) {                      \
      int base_ = w * 2048 + cc_ * 512;                                        \
      int row_ = w * 32 + cc_ * 8 + rsub;                                      \
      __builtin_amdgcn_global_load_lds(                                        \
          (const __attribute__((address_space(1))) void*)(gsrc_ +              \
              (size_t)row_ * (LD) + colb),                                     \
          (__attribute__((address_space(3))) void*)&LDSN[base_], 16, 0, 0);    \
    }                                                                          \
  }

// 128x128 output tile, one K=64 step from As/Bs; needs lane, wr, wc, acc
#define MFMA128x128x64()                                                       \
  _Pragma("unroll") for (int kk_ = 0; kk_ < 2; kk_++) {                        \
    bf16x8 af_[4], bf_[4];                                                     \
    int kcol_ = kk_ * 32 + (lane >> 4) * 8;                                    \
    _Pragma("unroll") for (int m_ = 0; m_ < 4; m_++)                           \
      af_[m_] = *(const bf16x8*)&As[(wr * 64 + m_ * 16 + (lane & 15)) * 64 + kcol_]; \
    _Pragma("unroll") for (int n_ = 0; n_ < 4; n_++)                           \
      bf_[n_] = *(const bf16x8*)&Bs[(wc * 64 + n_ * 16 + (lane & 15)) * 64 + kcol_]; \
    _Pragma("unroll") for (int m_ = 0; m_ < 4; m_++)                           \
      _Pragma("unroll") for (int n_ = 0; n_ < 4; n_++)                         \
        acc[m_][n_] = __builtin_amdgcn_mfma_f32_16x16x32_bf16(                 \
            af_[m_], bf_[n_], acc[m_][n_], 0, 0, 0);                           \
  }

#define MFMA_PROLOG()                                                          \
  const int tid = threadIdx.x;                                                 \
  const int lane = tid & 63;                                                   \
  const int w = tid >> 6;                                                      \
  const int wr = w >> 1, wc = w & 1;                                           \
  const int colb = (lane & 7) * 8;                                             \
  const int rsub = lane >> 3;                                                  \
  f32x4 acc[4][4] = {};                                                        \
  (void)colb; (void)rsub;

// ---------------------------------------------------------------------------
__global__ __launch_bounds__(256) void stack_wb(
    const float* __restrict__ Wq, const float* __restrict__ bq,
    const float* __restrict__ Wk, const float* __restrict__ bk,
    const float* __restrict__ Wv, const float* __restrict__ bv,
    unsigned short* __restrict__ Wstb, float* __restrict__ bst) {
  int idx = blockIdx.x * 256 + threadIdx.x;   // 640*512
  int row = idx >> 9;
  float val;
  if (row < 64)       val = Wq[idx];
  else if (row < 128) val = Wk[idx - (64 << 9)];
  else                val = Wv[idx - (128 << 9)];
  Wstb[idx] = f2bf(val);
  if (idx < OCH) {
    float bval;
    if (idx < 64)       bval = bq[idx];
    else if (idx < 128) bval = bk[idx - 64];
    else                bval = bv[idx - 128];
    bst[idx] = bval;
  }
}

__global__ __launch_bounds__(256) void prep_pcat(
    const float* __restrict__ rel_rows, const float* __restrict__ rel_cols,
    unsigned short* __restrict__ Pcatb) {
  int idx = blockIdx.x * 256 + threadIdx.x;   // 128*2304
  int dd = idx / NSP;
  int n = idx - dd * NSP;
  int xr = n / LL;
  int ic = n - xr * LL;
  int shift = ic - xr + (LL - 1);
  float val = (dd < 64) ? rel_rows[shift * 64 + dd] : rel_cols[shift * 64 + (dd - 64)];
  Pcatb[idx] = f2bf(val);
}

// x [b][c][n] fp32 -> xTb [b][n][c] bf16
__global__ __launch_bounds__(256) void transpose_x(
    const float* __restrict__ x, unsigned short* __restrict__ xTb) {
  __shared__ float t[64][65];
  const int n0 = blockIdx.x * 64;
  const int c0 = blockIdx.y * 64;
  const int b = blockIdx.z;
  const int j = threadIdx.x & 63;
  const int g = threadIdx.x >> 6;
  const float* xp = x + (size_t)b * CIN * NSP;
#pragma unroll
  for (int i = 0; i < 16; i++) {
    int cl = g * 16 + i;
    t[cl][j] = xp[(size_t)(c0 + cl) * NSP + n0 + j];
  }
  __syncthreads();
  unsigned short* op = xTb + (size_t)b * NSP * CIN;
#pragma unroll
  for (int i = 0; i < 16; i++) {
    int nl = g * 16 + i;
    op[(size_t)(n0 + nl) * CIN + c0 + j] = f2bf(t[j][nl]);
  }
}

// ---------------------------------------------------------------------------
// proj: y16[b,o,n] = bf16(sum_c Wstb[o,c]*xTb[b,n,c] + bst[o]); also emits
// per-block BN partial sums (s1,s2 per channel over this block's 128 cols)
__global__ __launch_bounds__(256) void proj_mfma(
    const unsigned short* __restrict__ Wstb, const float* __restrict__ bst,
    const unsigned short* __restrict__ xTb, unsigned short* __restrict__ y16,
    float* __restrict__ part1, float* __restrict__ part2) {
  __shared__ unsigned short As[128 * 64];
  __shared__ unsigned short Bs[128 * 64];
  int sw = ((blockIdx.x & 7) * 90) + (blockIdx.x >> 3);   // XCD swizzle, 720 wg
  const int rb = sw % 5;
  const int nb = (sw / 5) % 18;
  const int b = sw / 90;
  const int r0 = rb * 128;
  const int n0 = nb * 128;
  MFMA_PROLOG();
  const unsigned short* A = Wstb + (size_t)r0 * CIN;
  const unsigned short* B = xTb + (size_t)b * NSP * CIN + (size_t)n0 * CIN;
  for (int k0 = 0; k0 < CIN; k0 += 64) {
    STAGE128x64(A + k0, CIN, As);
    STAGE128x64(B + k0, CIN, Bs);
    __syncthreads();
    MFMA128x128x64();
    __syncthreads();
  }
  float* sp = (float*)As;   // [128][2] s1 then [128][2] s2
#pragma unroll
  for (int m = 0; m < 4; m++) {
#pragma unroll
    for (int r = 0; r < 4; r++) {
      int rl = wr * 64 + m * 16 + (lane >> 4) * 4 + r;
      int row = r0 + rl;
      float bias = bst[row];
      float s1 = 0.f, s2 = 0.f;
#pragma unroll
      for (int n = 0; n < 4; n++) {
        float yv = acc[m][n][r] + bias;
        s1 += yv;
        s2 += yv * yv;
        y16[((size_t)b * OCH + row) * NSP + n0 + wc * 64 + n * 16 + (lane & 15)] = f2bf(yv);
      }
#pragma unroll
      for (int off = 1; off < 16; off <<= 1) {
        s1 += __shfl_xor(s1, off);
        s2 += __shfl_xor(s2, off);
      }
      if ((lane & 15) == 0) {
        sp[rl * 2 + wc] = s1;
        sp[256 + rl * 2 + wc] = s2;
      }
    }
  }
  __syncthreads();
  if (tid < 128) {
    size_t pbase = ((size_t)b * 18 + nb) * OCH + r0 + tid;
    part1[pbase] = sp[tid * 2] + sp[tid * 2 + 1];
    part2[pbase] = sp[256 + tid * 2] + sp[256 + tid * 2 + 1];
  }
}

// reduce 144 partials/channel -> chanA/chanB
__global__ __launch_bounds__(256) void bn_finalize(
    const float* __restrict__ part1, const float* __restrict__ part2,
    const float* __restrict__ qs_, const float* __restrict__ qb_,
    const float* __restrict__ ks_, const float* __restrict__ kb_,
    const float* __restrict__ vs_, const float* __restrict__ vb_,
    float* __restrict__ chanA, float* __restrict__ chanB) {
  const int ch = blockIdx.x;
  const int tid = threadIdx.x;
  float s1 = 0.f, s2 = 0.f;
  for (int t = tid; t < 144; t += 256) {
    s1 += part1[(size_t)t * OCH + ch];
    s2 += part2[(size_t)t * OCH + ch];
  }
  __shared__ float sb[8];
#pragma unroll
  for (int off = 32; off > 0; off >>= 1) {
    s1 += __shfl_down(s1, off);
    s2 += __shfl_down(s2, off);
  }
  int lane = tid & 63, wid = tid >> 6;
  if (lane == 0) { sb[wid] = s1; sb[4 + wid] = s2; }
  __syncthreads();
  if (tid == 0) {
    float ts  = sb[0] + sb[1] + sb[2] + sb[3];
    float ts2 = sb[4] + sb[5] + sb[6] + sb[7];
    const float inv = 1.f / (float)(BB * NSP);
    float mean = ts * inv;
    float var  = ts2 * inv - mean * mean;
    float scale, bias;
    if (ch < 64)       { scale = qs_[ch];       bias = qb_[ch]; }
    else if (ch < 128) { scale = ks_[ch - 64];  bias = kb_[ch - 64]; }
    else               { scale = vs_[ch - 128]; bias = vb_[ch - 128]; }
    float a = scale * rsqrtf(var + 1e-5f);
    chanA[ch] = a;
    chanB[ch] = bias - mean * a;
  }
}

// in-place affine+relu on all of y16 (bf16)
__global__ __launch_bounds__(256) void bnrelu_all(
    unsigned short* __restrict__ y16, const float* __restrict__ chanA,
    const float* __restrict__ chanB) {
  size_t i = ((size_t)blockIdx.x * 256 + threadIdx.x) * 8;
  int ch = (int)((i / NSP) % OCH);
  float a = chanA[ch], bo = chanB[ch];
  ushort4 u0 = *(ushort4*)&y16[i];
  ushort4 u1 = *(ushort4*)&y16[i + 4];
  ushort4 o0, o1;
  o0.x = f2bf(fmaxf(0.f, a * bf2f(u0.x) + bo));
  o0.y = f2bf(fmaxf(0.f, a * bf2f(u0.y) + bo));
  o0.z = f2bf(fmaxf(0.f, a * bf2f(u0.z) + bo));
  o0.w = f2bf(fmaxf(0.f, a * bf2f(u0.w) + bo));
  o1.x = f2bf(fmaxf(0.f, a * bf2f(u1.x) + bo));
  o1.y = f2bf(fmaxf(0.f, a * bf2f(u1.y) + bo));
  o1.z = f2bf(fmaxf(0.f, a * bf2f(u1.z) + bo));
  o1.w = f2bf(fmaxf(0.f, a * bf2f(u1.w) + bo));
  *(ushort4*)&y16[i] = o0;
  *(ushort4*)&y16[i + 4] = o1;
}

// q/k channels [d][n] -> qTb/kTb [n][d], LDS-tiled, post-relu
__global__ __launch_bounds__(256) void tr_qk(
    const unsigned short* __restrict__ y16, unsigned short* __restrict__ qTb,
    unsigned short* __restrict__ kTb) {
  __shared__ unsigned short t[64][72];
  const int n0 = blockIdx.x * 64;
  const int qk = blockIdx.y;          // 0=q, 1=k
  const int b = blockIdx.z;
  const int j = threadIdx.x & 63;
  const int g = threadIdx.x >> 6;
#pragma unroll
  for (int i = 0; i < 16; i++) {
    int cl = g * 16 + i;
    t[cl][j] = y16[((size_t)b * OCH + qk * 64 + cl) * NSP + n0 + j];
  }
  __syncthreads();
  unsigned short* out = (qk == 0) ? qTb : kTb;
#pragma unroll
  for (int i = 0; i < 16; i++) {
    int nl = g * 16 + i;
    out[((size_t)b * NSP + n0 + nl) * 64 + j] = t[j][nl];
  }
}

// qs[b,d] = sum_n q[b,d,n] (post-relu, from y16)
__global__ __launch_bounds__(256) void qsum_kernel(
    const unsigned short* __restrict__ y16, float* __restrict__ qs) {
  int bd = blockIdx.x;
  int b = bd >> 6, d = bd & 63;
  const ushort4* p = (const ushort4*)(y16 + ((size_t)b * OCH + d) * NSP);
  float s = 0.f;
  for (int t = threadIdx.x; t < NSP / 4; t += 256) {
    ushort4 u = p[t];
    s += bf2f(u.x) + bf2f(u.y) + bf2f(u.z) + bf2f(u.w);
  }
  __shared__ float sb[4];
#pragma unroll
  for (int off = 32; off > 0; off >>= 1) s += __shfl_down(s, off);
  int lane = threadIdx.x & 63, wid = threadIdx.x >> 6;
  if (lane == 0) sb[wid] = s;
  __syncthreads();
  if (threadIdx.x == 0) qs[bd] = sb[0] + sb[1] + sb[2] + sb[3];
}

// Gq[b][d][e] = sum_i q[d,i]*q[e,i]  — bf16 MFMA, frag reuse, 4-wave split-K
__global__ __launch_bounds__(256) void gq_mfma(
    const unsigned short* __restrict__ y16, float* __restrict__ Gq) {
  __shared__ float wlds[4 * 4096];
  const int b = blockIdx.x;
  const int tid = threadIdx.x;
  const int lane = tid & 63;
  const int w = tid >> 6;
  const unsigned short* q = y16 + (size_t)b * OCH * NSP;
  f32x4 acc[4][4] = {};
  const int kbase = w * 576;
  for (int k0 = 0; k0 < 576; k0 += 32) {
    bf16x8 fr[4];
#pragma unroll
    for (int f = 0; f < 4; f++) {
      int row = f * 16 + (lane & 15);
      fr[f] = *(const bf16x8*)&q[(size_t)row * NSP + kbase + k0 + (lane >> 4) * 8];
    }
#pragma unroll
    for (int fm = 0; fm < 4; fm++)
#pragma unroll
      for (int fn = 0; fn < 4; fn++)
        acc[fm][fn] = __builtin_amdgcn_mfma_f32_16x16x32_bf16(
            fr[fm], fr[fn], acc[fm][fn], 0, 0, 0);
  }
#pragma unroll
  for (int fm = 0; fm < 4; fm++)
#pragma unroll
    for (int fn = 0; fn < 4; fn++)
#pragma unroll
      for (int r = 0; r < 4; r++) {
        int d = fm * 16 + (lane >> 4) * 4 + r;
        int e = fn * 16 + (lane & 15);
        wlds[w * 4096 + d * 64 + e] = acc[fm][fn][r];
      }
  __syncthreads();
  for (int t = tid; t < 4096; t += 256)
    Gq[(size_t)b * 4096 + t] =
        wlds[t] + wlds[4096 + t] + wlds[8192 + t] + wlds[12288 + t];
}

// ---------------------------------------------------------------------------
// energy+exp: Pp[b,i,j] = bf16(exp(qT[i]·kT[j])); also per-row partial sums
__global__ __launch_bounds__(256) void energy_mfma(
    const unsigned short* __restrict__ qTb, const unsigned short* __restrict__ kTb,
    unsigned short* __restrict__ Pp, float* __restrict__ Ppart) {
  __shared__ unsigned short As[128 * 64];
  __shared__ unsigned short Bs[128 * 64];
  int sw = ((blockIdx.x & 7) * 324) + (blockIdx.x >> 3);   // 2592 wg
  const int jb = sw % 18;
  const int ib = (sw / 18) % 18;
  const int b = sw / 324;
  const int i0 = ib * 128;
  const int j0 = jb * 128;
  MFMA_PROLOG();
  STAGE128x64(qTb + (size_t)b * NSP * 64 + (size_t)i0 * 64, 64, As);
  STAGE128x64(kTb + (size_t)b * NSP * 64 + (size_t)j0 * 64, 64, Bs);
  __syncthreads();
  MFMA128x128x64();
  __syncthreads();
  float* sp = (float*)As;
  unsigned short* pp = Pp + (size_t)b * NSP * NSP;
#pragma unroll
  for (int m = 0; m < 4; m++) {
#pragma unroll
    for (int r = 0; r < 4; r++) {
      int rl = wr * 64 + m * 16 + (lane >> 4) * 4 + r;
      int i = i0 + rl;
      float s1 = 0.f;
#pragma unroll
      for (int n = 0; n < 4; n++) {
        int j = j0 + wc * 64 + n * 16 + (lane & 15);
        unsigned short h = f2bf(__expf(acc[m][n][r]));
        pp[(size_t)i * NSP + j] = h;
        s1 += bf2f(h);
      }
#pragma unroll
      for (int off = 1; off < 16; off <<= 1) s1 += __shfl_xor(s1, off);
      if ((lane & 15) == 0) sp[rl * 2 + wc] = s1;
    }
  }
  __syncthreads();
  if (tid < 128)
    Ppart[((size_t)b * 18 + jb) * NSP + i0 + tid] = sp[tid * 2] + sp[tid * 2 + 1];
}

// rZ[row] = 1/sum_jb Ppart
__global__ __launch_bounds__(256) void zred_kernel(
    const float* __restrict__ Ppart, float* __restrict__ rZ) {
  int row = blockIdx.x * 256 + threadIdx.x;   // B*NSP
  int b = row / NSP, i = row % NSP;
  float s = 0.f;
#pragma unroll
  for (int jb = 0; jb < 18; jb++) s += Ppart[((size_t)b * 18 + jb) * NSP + i];
  rZ[row] = 1.f / s;
}

// ---------------------------------------------------------------------------
// Upart[kc][b][c][dd] = partial sum over k-chunk of v[c,n]*Pcat[dd,n]
__global__ __launch_bounds__(256) void up_mfma(
    const unsigned short* __restrict__ y16, const unsigned short* __restrict__ Pcatb,
    float* __restrict__ Upart) {
  __shared__ unsigned short As[128 * 64];
  __shared__ unsigned short Bs[128 * 64];
  int sw = ((blockIdx.x & 7) * 24) + (blockIdx.x >> 3);   // 192 wg
  const int cb = sw % 4;
  const int kc = (sw / 4) % 6;
  const int b = sw / 24;
  const int c0 = cb * 128;
  MFMA_PROLOG();
  const unsigned short* A = y16 + ((size_t)b * OCH + 128 + c0) * NSP;
  for (int k0 = kc * 384; k0 < kc * 384 + 384; k0 += 64) {
    STAGE128x64(A + k0, NSP, As);
    STAGE128x64(Pcatb + k0, NSP, Bs);
    __syncthreads();
    MFMA128x128x64();
    __syncthreads();
  }
  float* up = Upart + ((size_t)kc * BB + b) * CIN * 128 + (size_t)c0 * 128;
#pragma unroll
  for (int m = 0; m < 4; m++)
#pragma unroll
    for (int r = 0; r < 4; r++) {
      int rl = wr * 64 + m * 16 + (lane >> 4) * 4 + r;
#pragma unroll
      for (int n = 0; n < 4; n++) {
        int col = wc * 64 + n * 16 + (lane & 15);
        up[(size_t)rl * 128 + col] = acc[m][n][r];
      }
    }
}

__global__ __launch_bounds__(256) void up_reduce(
    const float* __restrict__ Upart, float* __restrict__ Ucat) {
  size_t idx = (size_t)blockIdx.x * 256 + threadIdx.x;   // 524288
  float s = 0.f;
#pragma unroll
  for (int kc = 0; kc < 6; kc++) s += Upart[(size_t)kc * 524288 + idx];
  Ucat[idx] = s;
}

// closed-form BN stats for Eh/Ew from Ucat ([0:64]=h, [64:128]=w)
__global__ __launch_bounds__(64) void rel_stats(
    const float* __restrict__ Ucat, const float* __restrict__ Gq,
    const float* __restrict__ qs,
    const float* __restrict__ bnr_s, const float* __restrict__ bnr_b,
    const float* __restrict__ bnc_s, const float* __restrict__ bnc_b,
    float* __restrict__ gh, float* __restrict__ gw, float* __restrict__ offc) {
  const int c = blockIdx.x;
  const int d = threadIdx.x;
  __shared__ float su[2][64];
  float s1h = 0.f, s2h = 0.f, s1w = 0.f, s2w = 0.f;
  for (int b = 0; b < BB; b++) {
    size_t base = ((size_t)b * CIN + c) * 128;
    float uh = Ucat[base + d];
    float uw = Ucat[base + 64 + d];
    __syncthreads();
    su[0][d] = uh;
    su[1][d] = uw;
    __syncthreads();
    const float* G = Gq + (size_t)b * 4096 + d * 64;
    float th = 0.f, tw = 0.f;
    for (int e = 0; e < 64; e++) {
      float g = G[e];
      th += g * su[0][e];
      tw += g * su[1][e];
    }
    float qsd = qs[b * 64 + d];
    s1h += uh * qsd;
    s2h += uh * th;
    s1w += uw * qsd;
    s2w += uw * tw;
  }
#pragma unroll
  for (int off = 32; off > 0; off >>= 1) {
    s1h += __shfl_down(s1h, off);
    s2h += __shfl_down(s2h, off);
    s1w += __shfl_down(s1w, off);
    s2w += __shfl_down(s2w, off);
  }
  if (d == 0) {
    const float inv = 1.f / (float)(BB * NSP);
    float mh = s1h * inv, vh = s2h * inv - mh * mh;
    float mw = s1w * inv, vw = s2w * inv - mw * mw;
    float gch = bnr_s[c] * rsqrtf(vh + 1e-5f);
    float gcw = bnc_s[c] * rsqrtf(vw + 1e-5f);
    gh[c] = gch;
    gw[c] = gcw;
    offc[c] = (bnr_b[c] - mh * gch) + (bnc_b[c] - mw * gcw);
  }
}

__global__ __launch_bounds__(256) void combine_u(
    const float* __restrict__ Ucat, const float* __restrict__ gh,
    const float* __restrict__ gw, unsigned short* __restrict__ Ucb) {
  int idx = blockIdx.x * 256 + threadIdx.x;  // B*512*64
  int d = idx & 63;
  int c = (idx >> 6) & 511;
  int b = idx >> 15;
  size_t base = ((size_t)b * CIN + c) * 128;
  Ucb[idx] = f2bf(Ucat[base + d] * gh[c] + Ucat[base + 64 + d] * gw[c]);
}

// ---------------------------------------------------------------------------
// fused: dst[c,i] = gamma*( rZ[i]*sum_j v[c,j]*Pp[i,j]
//                         + sum_d Ucb[c,d]*qT[i,d] + offc[c] ) + x[c,i]
__global__ __launch_bounds__(256) void attn_fused_gemm(
    const unsigned short* __restrict__ y16,   // v at channel offset 128
    const unsigned short* __restrict__ Pp,
    const float* __restrict__ rZ,
    const unsigned short* __restrict__ Ucb,
    const unsigned short* __restrict__ qTb,
    const float* __restrict__ offc,
    const float* __restrict__ gammap,
    const float* __restrict__ x,
    float* __restrict__ dst) {
  __shared__ unsigned short As[128 * 64];
  __shared__ unsigned short Bs[128 * 64];
  int sw = ((blockIdx.x & 7) * 72) + (blockIdx.x >> 3);   // 576 wg
  const int cb = sw % 4;
  const int ib = (sw / 4) % 18;
  const int b = sw / 72;
  const int c0 = cb * 128;
  const int i0 = ib * 128;
  MFMA_PROLOG();
  const unsigned short* A = y16 + ((size_t)b * OCH + 128 + c0) * NSP;
  const unsigned short* B = Pp + (size_t)b * NSP * NSP + (size_t)i0 * NSP;

  for (int j0 = 0; j0 < NSP; j0 += 64) {
    STAGE128x64(A + j0, NSP, As);
    STAGE128x64(B + j0, NSP, Bs);
    __syncthreads();
    MFMA128x128x64();
    __syncthreads();
  }

#pragma unroll
  for (int n = 0; n < 4; n++) {
    float rz = rZ[(size_t)b * NSP + i0 + wc * 64 + n * 16 + (lane & 15)];
#pragma unroll
    for (int m = 0; m < 4; m++)
#pragma unroll
      for (int r = 0; r < 4; r++) acc[m][n][r] *= rz;
  }

  STAGE128x64(Ucb + (size_t)b * CIN * 64 + (size_t)c0 * 64, 64, As);
  STAGE128x64(qTb + (size_t)b * NSP * 64 + (size_t)i0 * 64, 64, Bs);
  __syncthreads();
  MFMA128x128x64();

  const float gmm = gammap[0];
  const float* xp = x + (size_t)b * CIN * NSP;
  float* dp = dst + (size_t)b * CIN * NSP;
#pragma unroll
  for (int m = 0; m < 4; m++) {
#pragma unroll
    for (int r = 0; r < 4; r++) {
      int c = c0 + wr * 64 + m * 16 + (lane >> 4) * 4 + r;
      float off = offc[c];
#pragma unroll
      for (int n = 0; n < 4; n++) {
        int i = i0 + wc * 64 + n * 16 + (lane & 15);
        size_t o = (size_t)c * NSP + i;
        dp[o] = gmm * (acc[m][n][r] + off) + xp[o];
      }
    }
  }
}

// ---------------------------------------------------------------------------
extern "C" void kernel_launch(void* const* d_in, const int* in_sizes, int n_in,
                              void* d_out, int out_size, void* d_ws, size_t ws_size,
                              hipStream_t stream) {
  const float* x        = (const float*)d_in[0];
  const float* Wq       = (const float*)d_in[1];
  const float* bq       = (const float*)d_in[2];
  const float* q_scale  = (const float*)d_in[3];
  const float* q_bias   = (const float*)d_in[4];
  const float* Wk       = (const float*)d_in[5];
  const float* bk       = (const float*)d_in[6];
  const float* k_scale  = (const float*)d_in[7];
  const float* k_bias   = (const float*)d_in[8];
  const float* Wv       = (const float*)d_in[9];
  const float* bv       = (const float*)d_in[10];
  const float* v_scale  = (const float*)d_in[11];
  const float* v_bias   = (const float*)d_in[12];
  const float* rel_rows = (const float*)d_in[13];
  const float* rel_cols = (const float*)d_in[14];
  const float* bnr_s    = (const float*)d_in[15];
  const float* bnr_b    = (const float*)d_in[16];
  const float* bnc_s    = (const float*)d_in[17];
  const float* bnc_b    = (const float*)d_in[18];
  const float* gamma    = (const float*)d_in[19];
  float* dst = (float*)d_out;

  float* ws = (float*)d_ws;
  size_t o = 0;
  unsigned short* Wstb = (unsigned short*)(ws + o); o += (size_t)OCH * CIN / 2;
  float* bst    = ws + o; o += 1024;
  float* chanA  = ws + o; o += 1024;
  float* chanB  = ws + o; o += 1024;
  unsigned short* Pcatb = (unsigned short*)(ws + o); o += (size_t)128 * NSP / 2;
  unsigned short* y16 = (unsigned short*)(ws + o); o += (size_t)BB * OCH * NSP / 2;
  unsigned short* xTb = (unsigned short*)(ws + o); o += (size_t)BB * NSP * CIN / 2;
  unsigned short* Pp  = (unsigned short*)(ws + o); o += (size_t)BB * NSP * NSP / 2;
  float* Ppart  = ws + o; o += (size_t)BB * 18 * NSP;
  float* rZ     = ws + o; o += (size_t)BB * NSP;
  float* Upart  = ws + o; o += (size_t)6 * BB * CIN * 128;
  float* Ucat   = ws + o; o += (size_t)BB * CIN * 128;
  float* Gq     = ws + o; o += (size_t)BB * 64 * 64;
  float* part1  = ws + o; o += (size_t)BB * 18 * OCH;
  float* part2  = ws + o; o += (size_t)BB * 18 * OCH;
  float* qs     = ws + o; o += 1024;
  float* gh     = ws + o; o += 1024;
  float* gw     = ws + o; o += 1024;
  float* offc   = ws + o; o += 1024;
  unsigned short* qTb = (unsigned short*)(ws + o); o += (size_t)BB * NSP * 64 / 2;
  unsigned short* kTb = (unsigned short*)(ws + o); o += (size_t)BB * NSP * 64 / 2;
  unsigned short* Ucb = (unsigned short*)(ws + o); o += (size_t)BB * CIN * 64 / 2;

  stack_wb<<<(OCH * CIN) / 256, 256, 0, stream>>>(Wq, bq, Wk, bk, Wv, bv, Wstb, bst);
  prep_pcat<<<(128 * NSP) / 256, 256, 0, stream>>>(rel_rows, rel_cols, Pcatb);
  transpose_x<<<dim3(NSP / 64, CIN / 64, BB), 256, 0, stream>>>(x, xTb);

  proj_mfma<<<720, 256, 0, stream>>>(Wstb, bst, xTb, y16, part1, part2);
  bn_finalize<<<OCH, 256, 0, stream>>>(part1, part2, q_scale, q_bias, k_scale,
                                       k_bias, v_scale, v_bias, chanA, chanB);
  bnrelu_all<<<(int)((size_t)BB * OCH * NSP / 8 / 256), 256, 0, stream>>>(y16, chanA, chanB);
  tr_qk<<<dim3(NSP / 64, 2, BB), 256, 0, stream>>>(y16, qTb, kTb);
  qsum_kernel<<<BB * 64, 256, 0, stream>>>(y16, qs);
  gq_mfma<<<BB, 256, 0, stream>>>(y16, Gq);

  energy_mfma<<<2592, 256, 0, stream>>>(qTb, kTb, Pp, Ppart);
  zred_kernel<<<BB * NSP / 256, 256, 0, stream>>>(Ppart, rZ);

  up_mfma<<<192, 256, 0, stream>>>(y16, Pcatb, Upart);
  up_reduce<<<2048, 256, 0, stream>>>(Upart, Ucat);
  rel_stats<<<CIN, 64, 0, stream>>>(Ucat, Gq, qs, bnr_s, bnr_b, bnc_s, bnc_b,
                                    gh, gw, offc);
  combine_u<<<(BB * CIN * 64) / 256, 256, 0, stream>>>(Ucat, gh, gw, Ucb);

  attn_fused_gemm<<<576, 256, 0, stream>>>(y16, Pp, rZ, Ucb, qTb, offc, gamma, x, dst);
}